// Round 10
// baseline (169.172 us; speedup 1.0000x reference)
//
#include <hip/hip_runtime.h>

#define BT 32
#define CH 64
#define HS 56
#define WS 56
#define HH 28
#define WH 28

// ---------------- filter constants (exact reference values) ----------------
namespace {
constexpr float ISQ2 = 0.70710678118654752440f;
constexpr float F_H0[13] = {-0.0017578125f, 0.0f, 0.022265625f, -0.046875f,
    -0.0482421875f, 0.296875f, 0.55546875f, 0.296875f, -0.0482421875f,
    -0.046875f, 0.022265625f, 0.0f, -0.0017578125f};
constexpr float F_H1[19] = {-7.0626e-05f, 0.0f, 0.00134189f, -0.00188341f,
    -0.0071566f, 0.023856f, 0.0556431f, -0.0516881f, -0.299758f, 0.559431f,
    -0.299758f, -0.0516881f, 0.0556431f, 0.023856f, -0.0071566f,
    -0.00188341f, 0.00134189f, 0.0f, -7.0626e-05f};
constexpr float F_G0[19] = {7.0626e-05f, 0.0f, -0.00134189f, -0.00188341f,
    0.0071566f, 0.023856f, -0.0556431f, -0.0516881f, 0.299758f, 0.559431f,
    0.299758f, -0.0516881f, -0.0556431f, 0.023856f, 0.0071566f,
    -0.00188341f, -0.00134189f, 0.0f, 7.0626e-05f};
constexpr float F_G1[13] = {-0.0017578125f, 0.0f, 0.022265625f, 0.046875f,
    -0.0482421875f, -0.296875f, 0.55546875f, -0.296875f, -0.0482421875f,
    0.046875f, 0.022265625f, 0.0f, -0.0017578125f};
}

__device__ __forceinline__ int symi(int k) {
    k = (k < 0) ? (-1 - k) : k;
    k = (k >= HS) ? (2 * HS - 1 - k) : k;
    return k;
}

__device__ __forceinline__ unsigned short f2bf(float f) {  // RNE bf16
    unsigned u = __float_as_uint(f);
    u += 0x7fffu + ((u >> 16) & 1u);
    return (unsigned short)(u >> 16);
}
__device__ __forceinline__ float bf2f(unsigned short h) {
    return __uint_as_float(((unsigned)h) << 16);
}
// unpack 2 packed bf16 (channels c0, c0+1) from one dword
__device__ __forceinline__ float2 bfp2(unsigned u) {
    float2 r;
    r.x = __uint_as_float((u & 0xffffu) << 16);
    r.y = __uint_as_float(u & 0xffff0000u);
    return r;
}
__device__ __forceinline__ unsigned packbf(float a, float b) {
    return (unsigned)f2bf(a) | ((unsigned)f2bf(b) << 16);
}

typedef __attribute__((ext_vector_type(8))) short short8;  // 8 bf16 (4 VGPR)
typedef __attribute__((ext_vector_type(4))) float f32x4;

// sbT layout: [p 12][b 32][pos 784][c 64], bf16.
#define PPOS 784

// ---- K1: forward row filters: x -> lo, hi (bf16).
// Blocks 0..48 additionally transpose w_ll -> wllT (folds old k_wll_T launch).
__global__ __launch_bounds__(256) void k_fwd_rows(const float* __restrict__ x,
                                                  unsigned short* __restrict__ lo,
                                                  unsigned short* __restrict__ hi,
                                                  const float* __restrict__ wll,
                                                  float* __restrict__ wllT) {
    int b = blockIdx.x / HS, h = blockIdx.x % HS;
    int strip = threadIdx.x >> 5;        // 0..7 strips of 7 w
    int c0 = (threadIdx.x & 31) * 2;
    int base = (b * HS + h) * WS * CH + c0;
    const float* row = x + base;
    unsigned short* lop = lo + base;
    unsigned short* hip = hi + base;
    int w0s = strip * 7;
    float Wa[19], Wb[19];
#pragma unroll
    for (int t = 0; t < 19; ++t) {
        float2 v = *(const float2*)(row + symi(w0s - 9 + t) * CH);
        Wa[t] = v.x; Wb[t] = v.y;
    }
    float2 nW[7];
#pragma unroll
    for (int u = 0; u < 7; ++u) nW[u] = *(const float2*)(row + symi(w0s + u + 10) * CH);
#pragma unroll
    for (int u = 0; u < 7; ++u) {
        int w = w0s + u;
        float aLo = 0.f, aHi = 0.f, bLo = 0.f, bHi = 0.f;
#pragma unroll
        for (int t = 0; t < 13; ++t) { aLo += F_H0[t] * Wa[3 + t]; bLo += F_H0[t] * Wb[3 + t]; }
#pragma unroll
        for (int t = 0; t < 19; ++t) { aHi += F_H1[t] * Wa[t]; bHi += F_H1[t] * Wb[t]; }
        *(unsigned*)(lop + w * CH) = packbf(aLo, bLo);
        *(unsigned*)(hip + w * CH) = packbf(aHi, bHi);
#pragma unroll
        for (int t = 0; t < 18; ++t) { Wa[t] = Wa[t + 1]; Wb[t] = Wb[t + 1]; }
        Wa[18] = nW[u].x; Wb[18] = nW[u].y;
    }
    // ---- folded w_ll transpose (uniform per-block branch; 49 blocks) ----
    if (blockIdx.x < 49) {
        __shared__ float tile[64][65];
        int pos0 = blockIdx.x * 64;
        int lp = threadIdx.x & 63, g = threadIdx.x >> 6;
#pragma unroll
        for (int r = 0; r < 16; ++r) {
            int cc = r * 4 + g;
            tile[cc][lp] = wll[cc * (HS * WS) + pos0 + lp];
        }
        __syncthreads();
#pragma unroll
        for (int r = 0; r < 16; ++r) {
            int pl = r * 4 + g;
            wllT[(pos0 + pl) * CH + lp] = tile[lp][pl];
        }
    }
}

// ---- K2: merged column filters (z=0: lo path, z=1: hi path), hf=2 halves.
// qT staged as bf16 [src][q][14][c] (14.3 KB LDS) + prefetch in 2 rounds of 7
// (VGPR ~60) -> occupancy 20 -> ~28-32 waves/CU. xl output bf16.
__global__ __launch_bounds__(256) void k_cols(
    const unsigned short* __restrict__ lo_in,
    const unsigned short* __restrict__ hi_in, const float* __restrict__ wllT,
    unsigned short* __restrict__ xl, unsigned short* __restrict__ sbT) {
    __shared__ unsigned short qTb[2][4][14][64];  // 14.3 KB bf16
    int hf = blockIdx.y;
    int zmode = blockIdx.z;            // uniform branch
    int b = blockIdx.x / WH, wp = blockIdx.x % WH;
    int w0 = 2 * wp, tid = threadIdx.x;
    int q = tid >> 6, c = tid & 63;
    int rp = q >> 1, jc = q & 1;
    const unsigned short* srcp = zmode ? hi_in : lo_in;
    const unsigned short* colbase = srcp + (b * HS) * WS * CH + (w0 + jc) * CH + c;
    {
        int hstart = 2 * (hf * 14) + rp;
        float W[19];
#pragma unroll
        for (int t = 0; t < 19; ++t) W[t] = bf2f(colbase[symi(hstart - 9 + t) * (WS * CH)]);
        for (int rnd = 0; rnd < 2; ++rnd) {
            float nW0[7], nW1[7], nwll[7];
            int ii0 = rnd * 7;
#pragma unroll
            for (int u = 0; u < 7; ++u) {
                int h = hstart + 2 * (ii0 + u);
                nW0[u] = bf2f(colbase[symi(h + 10) * (WS * CH)]);
                nW1[u] = bf2f(colbase[symi(h + 11) * (WS * CH)]);
            }
            if (zmode == 0) {
#pragma unroll
                for (int u = 0; u < 7; ++u)
                    nwll[u] = wllT[((hstart + 2 * (ii0 + u)) * WS + (w0 + jc)) * CH + c];
            }
#pragma unroll
            for (int u = 0; u < 7; ++u) {
                int ii = ii0 + u;
                int h = hstart + 2 * ii;
                float v0 = 0.f, v1 = 0.f;
#pragma unroll
                for (int t = 0; t < 13; ++t) v0 += F_H0[t] * W[3 + t];
#pragma unroll
                for (int t = 0; t < 19; ++t) v1 += F_H1[t] * W[t];
                if (zmode == 0) {
                    xl[((b * HS + h) * WS + (w0 + jc)) * CH + c] = f2bf(v0 * nwll[u]);
                    qTb[0][q][ii][c] = f2bf(v1);
                } else {
                    qTb[0][q][ii][c] = f2bf(v0);   // hl
                    qTb[1][q][ii][c] = f2bf(v1);   // hh
                }
#pragma unroll
                for (int t = 0; t < 17; ++t) W[t] = W[t + 2];
                W[17] = nW0[u];
                W[18] = nW1[u];
            }
        }
    }
    __syncthreads();
    // fused q2c + bf16 pack: role 0:(a-d) 1:(b+c) 2:(a+d) 3:(b-c)
    {
        int qq = tid >> 5;                 // 0..7
        int role = qq & 3, half = qq >> 2; // ii 0..6 / 7..13
        int c0 = (tid & 31) * 2;
        int rowA = role & 1, rowB = 3 - (role & 1);
        float sgn = (role == 1 || role == 2) ? 1.f : -1.f;
        int posb = wp * 28 + hf * 14;
        if (zmode == 0) {
            int p = (role < 2) ? role : role + 8;  // planes 0,1,10,11
            unsigned short* dst = sbT + ((p * BT + b) * PPOS + posb) * CH + c0;
#pragma unroll
            for (int g = 0; g < 7; ++g) {
                int ii = half * 7 + g;
                float2 av = bfp2(*(const unsigned*)&qTb[0][rowA][ii][c0]);
                float2 bv = bfp2(*(const unsigned*)&qTb[0][rowB][ii][c0]);
                float v0 = (av.x + sgn * bv.x) * ISQ2;
                float v1 = (av.y + sgn * bv.y) * ISQ2;
                *(unsigned*)(dst + ii * CH) = packbf(v0, v1);
            }
        } else {
#pragma unroll
            for (int src = 0; src < 2; ++src) {
                // src0 (hl): planes 4..7; src1 (hh): planes 2,3,8,9
                int p = (src == 0) ? (4 + role) : ((role < 2) ? (2 + role) : (6 + role));
                unsigned short* dst = sbT + ((p * BT + b) * PPOS + posb) * CH + c0;
#pragma unroll
                for (int g = 0; g < 7; ++g) {
                    int ii = half * 7 + g;
                    float2 av = bfp2(*(const unsigned*)&qTb[src][rowA][ii][c0]);
                    float2 bv = bfp2(*(const unsigned*)&qTb[src][rowB][ii][c0]);
                    float v0 = (av.x + sgn * bv.x) * ISQ2;
                    float v1 = (av.y + sgn * bv.y) * ISQ2;
                    *(unsigned*)(dst + ii * CH) = packbf(v0, v1);
                }
            }
        }
    }
}

// ---- K3: MFMA channel mixing + fused c2q -> bf16 planes P[b][h][w][c]
// One 16-pos tile per block; grid 3*BT*49 = 4704 blocks; 4-wave blocks (wv=nb).
__global__ __launch_bounds__(256) void k_mix(
    const unsigned short* __restrict__ sbT, const float* __restrict__ w1,
    const float* __restrict__ w2, const float* __restrict__ b1,
    const float* __restrict__ b2, unsigned short* __restrict__ P0,
    unsigned short* __restrict__ P1, unsigned short* __restrict__ P2) {
    __shared__ unsigned short l1a[4][16][36];
    __shared__ unsigned short l1b[4][16][36];
    int blk = blockIdx.x;
    int pr = blk / (BT * 49);
    int rem = blk % (BT * 49);
    int b = rem / 49;
    int tile = rem % 49;
    int sa = (pr == 0) ? 0 : (pr == 1) ? 2 : 1;
    int sb = (pr == 0) ? 5 : (pr == 1) ? 3 : 4;
    unsigned short* Pd = (pr == 0) ? P0 : (pr == 1) ? P1 : P2;
    int tid = threadIdx.x;
    int lane = tid & 63;
    int wv = tid >> 6;
    int nb = __builtin_amdgcn_readfirstlane(wv);
    int quad = lane >> 4;
    int n = lane & 15;

    // A-fragment loads issued FIRST (hide under weight-load chain)
    int rix = quad >> 1, dlo = (quad & 1) * 8;
    int pos0 = tile * 16;
    const unsigned short* pAa =
        sbT + (((sa * 2 + rix) * BT + b) * PPOS + pos0 + n) * CH + nb * 16 + dlo;
    const unsigned short* pAb =
        sbT + (((sb * 2 + rix) * BT + b) * PPOS + pos0 + n) * CH + nb * 16 + dlo;
    short8 A1a = *(const short8*)pAa;
    short8 A1b = *(const short8*)pAb;

    short8 B1r, B1i, B2r, B2i;
#pragma unroll
    for (int j = 0; j < 8; ++j) {
        int kk = quad * 8 + j;
        int riw = kk >> 4, dd = kk & 15;
        float v1r = w1[nb * 256 + dd * 16 + n];
        float v1i = w1[1024 + nb * 256 + dd * 16 + n];
        float v2r = w2[nb * 256 + dd * 16 + n];
        float v2i = w2[1024 + nb * 256 + dd * 16 + n];
        B1r[j] = (short)f2bf(riw ? -v1i : v1r);
        B1i[j] = (short)f2bf(riw ? v1r : v1i);
        B2r[j] = (short)f2bf(riw ? -v2i : v2r);
        B2i[j] = (short)f2bf(riw ? v2r : v2i);
    }
    float bias1r = b1[nb * 16 + n], bias1i = b1[64 + nb * 16 + n];
    float bias2r = b2[nb * 16 + n], bias2i = b2[64 + nb * 16 + n];

    f32x4 a1r = {bias1r, bias1r, bias1r, bias1r};
    f32x4 a1i = {bias1i, bias1i, bias1i, bias1i};
    f32x4 b1r_ = a1r, b1i_ = a1i;
    a1r = __builtin_amdgcn_mfma_f32_16x16x32_bf16(A1a, B1r, a1r, 0, 0, 0);
    a1i = __builtin_amdgcn_mfma_f32_16x16x32_bf16(A1a, B1i, a1i, 0, 0, 0);
    b1r_ = __builtin_amdgcn_mfma_f32_16x16x32_bf16(A1b, B1r, b1r_, 0, 0, 0);
    b1i_ = __builtin_amdgcn_mfma_f32_16x16x32_bf16(A1b, B1i, b1i_, 0, 0, 0);
#pragma unroll
    for (int r = 0; r < 4; ++r) {
        int pos = quad * 4 + r;
        l1a[wv][pos][n] = f2bf(fmaxf(a1r[r], 0.f));
        l1a[wv][pos][16 + n] = f2bf(fmaxf(a1i[r], 0.f));
        l1b[wv][pos][n] = f2bf(fmaxf(b1r_[r], 0.f));
        l1b[wv][pos][16 + n] = f2bf(fmaxf(b1i_[r], 0.f));
    }
    union { short8 s8; uint2 u2[2]; } a2a, a2b;
    const unsigned short* rowpa = &l1a[wv][n][0];
    const unsigned short* rowpb = &l1b[wv][n][0];
    a2a.u2[0] = *(const uint2*)(rowpa + quad * 8);
    a2a.u2[1] = *(const uint2*)(rowpa + quad * 8 + 4);
    a2b.u2[0] = *(const uint2*)(rowpb + quad * 8);
    a2b.u2[1] = *(const uint2*)(rowpb + quad * 8 + 4);
    f32x4 aAr = {bias2r, bias2r, bias2r, bias2r};
    f32x4 aAi = {bias2i, bias2i, bias2i, bias2i};
    f32x4 aBr = aAr, aBi = aAi;
    aAr = __builtin_amdgcn_mfma_f32_16x16x32_bf16(a2a.s8, B2r, aAr, 0, 0, 0);
    aAi = __builtin_amdgcn_mfma_f32_16x16x32_bf16(a2a.s8, B2i, aAi, 0, 0, 0);
    aBr = __builtin_amdgcn_mfma_f32_16x16x32_bf16(a2b.s8, B2r, aBr, 0, 0, 0);
    aBi = __builtin_amdgcn_mfma_f32_16x16x32_bf16(a2b.s8, B2i, aBi, 0, 0, 0);
#pragma unroll
    for (int r = 0; r < 4; ++r) {
        int pos_g = pos0 + quad * 4 + r;
        int wp = pos_g / 28, ii = pos_g - wp * 28;
        int o = ((b * HS + 2 * ii) * WS + 2 * wp) * CH + nb * 16 + n;
        Pd[o] = f2bf((aAr[r] + aBr[r]) * ISQ2);
        Pd[o + CH] = f2bf((aAi[r] + aBi[r]) * ISQ2);
        Pd[o + WS * CH] = f2bf((aAi[r] - aBi[r]) * ISQ2);
        Pd[o + WS * CH + CH] = f2bf((aBr[r] - aAr[r]) * ISQ2);
    }
}

// ---- K4: inverse column pass, templated on mode (uniform blockIdx.z):
//   MODE=0: lo2 = G0col(xl bf16) + G1col(P0);  MODE=1: hi2 = G0col(P1) + G1col(P2)
// H-quarter split (blockIdx.y=4, 14 outputs) for occupancy (7 blocks/CU);
// 2-deep software-pipelined groups {4,4,4,2}. Outputs bf16.
template <int MODE>
__device__ __forceinline__ void inv_cols_body(
    const unsigned short* __restrict__ xl, const unsigned short* __restrict__ P0,
    const unsigned short* __restrict__ P1, const unsigned short* __restrict__ P2,
    unsigned short* __restrict__ lo2, unsigned short* __restrict__ hi2) {
    int hf = blockIdx.y;               // 0..3
    int b = blockIdx.x / 7, wg = blockIdx.x % 7;
    int wl = threadIdx.x >> 5, l = threadIdx.x & 31;
    int c0 = l * 2;
    int w = wg * 8 + wl;
    int base = (b * HS) * WS * CH + w * CH + c0;
    const int st = WS * CH;
    const unsigned short* Ap = (MODE == 0) ? xl : P1;
    const unsigned short* Bp = (MODE == 0) ? P0 : P2;
    unsigned short* outp = (MODE == 0) ? lo2 : hi2;
    auto ldA = [&](int r) -> float2 {
        return bfp2(*(const unsigned*)(Ap + base + r * st));
    };
    auto ldB = [&](int r) -> float2 {
        return bfp2(*(const unsigned*)(Bp + base + r * st));
    };
    int h0 = hf * 14;
    float Aa[19], Ab[19], Ba[13], Bb[13];
#pragma unroll
    for (int t = 0; t < 19; ++t) { float2 v = ldA(symi(h0 - 9 + t)); Aa[t] = v.x; Ab[t] = v.y; }
#pragma unroll
    for (int t = 0; t < 13; ++t) { float2 v = ldB(symi(h0 - 6 + t)); Ba[t] = v.x; Bb[t] = v.y; }
    float2 pa0[4], pb0[4], pa1[4], pb1[4];
#define LDG(bA, bB, OFF, CNT)                                                   \
    {                                                                           \
        _Pragma("unroll") for (int u = 0; u < (CNT); ++u)                       \
            bA[u] = ldA(symi(h0 + (OFF) + u + 10));                             \
        _Pragma("unroll") for (int u = 0; u < (CNT); ++u)                       \
            bB[u] = ldB(symi(h0 + (OFF) + u + 7));                              \
    }
#define CPG(bA, bB, OFF, CNT)                                                   \
    {                                                                           \
        _Pragma("unroll") for (int u = 0; u < (CNT); ++u) {                     \
            int h = h0 + (OFF) + u;                                             \
            float acca = 0.f, accb = 0.f;                                       \
            _Pragma("unroll") for (int t = 0; t < 19; ++t) {                    \
                acca += F_G0[t] * Aa[t]; accb += F_G0[t] * Ab[t];               \
            }                                                                   \
            _Pragma("unroll") for (int t = 0; t < 13; ++t) {                    \
                acca += F_G1[t] * Ba[t]; accb += F_G1[t] * Bb[t];               \
            }                                                                   \
            *(unsigned*)(outp + base + h * st) = packbf(acca, accb);            \
            _Pragma("unroll") for (int t = 0; t < 18; ++t) {                    \
                Aa[t] = Aa[t + 1]; Ab[t] = Ab[t + 1];                           \
            }                                                                   \
            _Pragma("unroll") for (int t = 0; t < 12; ++t) {                    \
                Ba[t] = Ba[t + 1]; Bb[t] = Bb[t + 1];                           \
            }                                                                   \
            Aa[18] = bA[u].x; Ab[18] = bA[u].y;                                 \
            Ba[12] = bB[u].x; Bb[12] = bB[u].y;                                 \
        }                                                                       \
    }
    LDG(pa0, pb0, 0, 4) LDG(pa1, pb1, 4, 4)
    CPG(pa0, pb0, 0, 4) LDG(pa0, pb0, 8, 4)
    CPG(pa1, pb1, 4, 4) LDG(pa1, pb1, 12, 2)
    CPG(pa0, pb0, 8, 4)
    CPG(pa1, pb1, 12, 2)
#undef LDG
#undef CPG
}

__global__ __launch_bounds__(256) void k_inv_cols(
    const unsigned short* __restrict__ xl, const unsigned short* __restrict__ P0,
    const unsigned short* __restrict__ P1, const unsigned short* __restrict__ P2,
    unsigned short* __restrict__ lo2, unsigned short* __restrict__ hi2) {
    if (blockIdx.z == 0)
        inv_cols_body<0>(xl, P0, P1, P2, lo2, hi2);
    else
        inv_cols_body<1>(xl, P0, P1, P2, lo2, hi2);
}

// ---- K5: inverse row filters (bf16 in) -> out (fp32), 2ch/thread, batched
__global__ __launch_bounds__(256) void k_inv_rows(
    const unsigned short* __restrict__ lo2,
    const unsigned short* __restrict__ hi2, float* __restrict__ out) {
    int b = blockIdx.x / HS, h = blockIdx.x % HS;
    int strip = threadIdx.x >> 5;        // 0..7 strips of 7 w
    int c0 = (threadIdx.x & 31) * 2;
    int base = (b * HS + h) * WS * CH + c0;
    const unsigned short* rlo = lo2 + base;
    const unsigned short* rhi = hi2 + base;
    float* op = out + base;
    int w0s = strip * 7;
    float Aa[19], Ab[19], Ba[13], Bb[13];
#pragma unroll
    for (int t = 0; t < 19; ++t) {
        float2 v = bfp2(*(const unsigned*)(rlo + symi(w0s - 9 + t) * CH));
        Aa[t] = v.x; Ab[t] = v.y;
    }
#pragma unroll
    for (int t = 0; t < 13; ++t) {
        float2 v = bfp2(*(const unsigned*)(rhi + symi(w0s - 6 + t) * CH));
        Ba[t] = v.x; Bb[t] = v.y;
    }
    float2 nA[7], nB[7];
#pragma unroll
    for (int u = 0; u < 7; ++u) nA[u] = bfp2(*(const unsigned*)(rlo + symi(w0s + u + 10) * CH));
#pragma unroll
    for (int u = 0; u < 7; ++u) nB[u] = bfp2(*(const unsigned*)(rhi + symi(w0s + u + 7) * CH));
#pragma unroll
    for (int u = 0; u < 7; ++u) {
        int w = w0s + u;
        float acca = 0.f, accb = 0.f;
#pragma unroll
        for (int t = 0; t < 19; ++t) { acca += F_G0[t] * Aa[t]; accb += F_G0[t] * Ab[t]; }
#pragma unroll
        for (int t = 0; t < 13; ++t) { acca += F_G1[t] * Ba[t]; accb += F_G1[t] * Bb[t]; }
        float2 ov; ov.x = acca; ov.y = accb;
        *(float2*)(op + w * CH) = ov;
#pragma unroll
        for (int t = 0; t < 18; ++t) { Aa[t] = Aa[t + 1]; Ab[t] = Ab[t + 1]; }
#pragma unroll
        for (int t = 0; t < 12; ++t) { Ba[t] = Ba[t + 1]; Bb[t] = Bb[t + 1]; }
        Aa[18] = nA[u].x; Ab[18] = nA[u].y;
        Ba[12] = nB[u].x; Bb[12] = nB[u].y;
    }
}

extern "C" void kernel_launch(void* const* d_in, const int* in_sizes, int n_in,
                              void* d_out, int out_size, void* d_ws, size_t ws_size,
                              hipStream_t stream) {
    const float* x = (const float*)d_in[0];
    const float* w_ll = (const float*)d_in[1];
    const float* w1 = (const float*)d_in[2];
    const float* w2 = (const float*)d_in[3];
    const float* b1 = (const float*)d_in[4];
    const float* b2 = (const float*)d_in[5];
    float* out = (float*)d_out;

    // workspace map (float units). A = 6,422,528; SBf = 9,633,792.
    // xl(bf16, region A) | sbT(->lo2 bf16) | hi2 bf16 | lo_in | hi_in | P0|P1|P2
    const size_t A = (size_t)BT * HS * WS * CH;
    const size_t SBf = (size_t)12 * 64 * BT * PPOS / 2;
    float* wsf = (float*)d_ws;
    unsigned short* xl = (unsigned short*)wsf;          // bf16 (region oversized)
    unsigned short* sbT = (unsigned short*)(wsf + A);   // dead after mix
    unsigned short* lo2 = (unsigned short*)(wsf + A);   //   .. reuses sbT region
    unsigned short* hi2 = (unsigned short*)(wsf + A + SBf);
    unsigned short* lo_in = (unsigned short*)(wsf + A + SBf + A);
    unsigned short* hi_in = lo_in + A;                  // bf16
    unsigned short* P0 = hi_in + A;                     // bf16
    unsigned short* P1 = P0 + A;
    unsigned short* P2 = P1 + A;

    float* wllT = out;  // staged in d_out head (overwritten by k_inv_rows)

    k_fwd_rows<<<BT * HS, 256, 0, stream>>>(x, lo_in, hi_in, w_ll, wllT);
    k_cols<<<dim3(BT * WH, 2, 2), 256, 0, stream>>>(lo_in, hi_in, wllT, xl, sbT);
    k_mix<<<3 * BT * 49, 256, 0, stream>>>(sbT, w1, w2, b1, b2, P0, P1, P2);
    k_inv_cols<<<dim3(BT * 7, 4, 2), 256, 0, stream>>>(xl, P0, P1, P2, lo2, hi2);
    k_inv_rows<<<BT * HS, 256, 0, stream>>>(lo2, hi2, out);
}

// Round 11
// 162.799 us; speedup vs baseline: 1.0392x; 1.0392x over previous
//
#include <hip/hip_runtime.h>

#define BT 32
#define CH 64
#define HS 56
#define WS 56
#define HH 28
#define WH 28

// ---------------- filter constants (exact reference values) ----------------
namespace {
constexpr float ISQ2 = 0.70710678118654752440f;
constexpr float F_H0[13] = {-0.0017578125f, 0.0f, 0.022265625f, -0.046875f,
    -0.0482421875f, 0.296875f, 0.55546875f, 0.296875f, -0.0482421875f,
    -0.046875f, 0.022265625f, 0.0f, -0.0017578125f};
constexpr float F_H1[19] = {-7.0626e-05f, 0.0f, 0.00134189f, -0.00188341f,
    -0.0071566f, 0.023856f, 0.0556431f, -0.0516881f, -0.299758f, 0.559431f,
    -0.299758f, -0.0516881f, 0.0556431f, 0.023856f, -0.0071566f,
    -0.00188341f, 0.00134189f, 0.0f, -7.0626e-05f};
constexpr float F_G0[19] = {7.0626e-05f, 0.0f, -0.00134189f, -0.00188341f,
    0.0071566f, 0.023856f, -0.0556431f, -0.0516881f, 0.299758f, 0.559431f,
    0.299758f, -0.0516881f, -0.0556431f, 0.023856f, 0.0071566f,
    -0.00188341f, -0.00134189f, 0.0f, 7.0626e-05f};
constexpr float F_G1[13] = {-0.0017578125f, 0.0f, 0.022265625f, 0.046875f,
    -0.0482421875f, -0.296875f, 0.55546875f, -0.296875f, -0.0482421875f,
    0.046875f, 0.022265625f, 0.0f, -0.0017578125f};
}

__device__ __forceinline__ int symi(int k) {
    k = (k < 0) ? (-1 - k) : k;
    k = (k >= HS) ? (2 * HS - 1 - k) : k;
    return k;
}

__device__ __forceinline__ unsigned short f2bf(float f) {  // RNE bf16
    unsigned u = __float_as_uint(f);
    u += 0x7fffu + ((u >> 16) & 1u);
    return (unsigned short)(u >> 16);
}
__device__ __forceinline__ float bf2f(unsigned short h) {
    return __uint_as_float(((unsigned)h) << 16);
}
// unpack 2 packed bf16 (channels c0, c0+1) from one dword
__device__ __forceinline__ float2 bfp2(unsigned u) {
    float2 r;
    r.x = __uint_as_float((u & 0xffffu) << 16);
    r.y = __uint_as_float(u & 0xffff0000u);
    return r;
}
__device__ __forceinline__ unsigned packbf(float a, float b) {
    return (unsigned)f2bf(a) | ((unsigned)f2bf(b) << 16);
}

typedef __attribute__((ext_vector_type(8))) short short8;  // 8 bf16 (4 VGPR)
typedef __attribute__((ext_vector_type(4))) float f32x4;

#define PPOS 784

// ---- K1: forward row filters: x -> lo, hi (bf16).
// Blocks 0..48 additionally transpose w_ll -> wllT (folds old k_wll_T launch).
__global__ __launch_bounds__(256) void k_fwd_rows(const float* __restrict__ x,
                                                  unsigned short* __restrict__ lo,
                                                  unsigned short* __restrict__ hi,
                                                  const float* __restrict__ wll,
                                                  float* __restrict__ wllT) {
    int b = blockIdx.x / HS, h = blockIdx.x % HS;
    int strip = threadIdx.x >> 5;        // 0..7 strips of 7 w
    int c0 = (threadIdx.x & 31) * 2;
    int base = (b * HS + h) * WS * CH + c0;
    const float* row = x + base;
    unsigned short* lop = lo + base;
    unsigned short* hip = hi + base;
    int w0s = strip * 7;
    float Wa[19], Wb[19];
#pragma unroll
    for (int t = 0; t < 19; ++t) {
        float2 v = *(const float2*)(row + symi(w0s - 9 + t) * CH);
        Wa[t] = v.x; Wb[t] = v.y;
    }
    float2 nW[7];
#pragma unroll
    for (int u = 0; u < 7; ++u) nW[u] = *(const float2*)(row + symi(w0s + u + 10) * CH);
#pragma unroll
    for (int u = 0; u < 7; ++u) {
        int w = w0s + u;
        float aLo = 0.f, aHi = 0.f, bLo = 0.f, bHi = 0.f;
#pragma unroll
        for (int t = 0; t < 13; ++t) { aLo += F_H0[t] * Wa[3 + t]; bLo += F_H0[t] * Wb[3 + t]; }
#pragma unroll
        for (int t = 0; t < 19; ++t) { aHi += F_H1[t] * Wa[t]; bHi += F_H1[t] * Wb[t]; }
        *(unsigned*)(lop + w * CH) = packbf(aLo, bLo);
        *(unsigned*)(hip + w * CH) = packbf(aHi, bHi);
#pragma unroll
        for (int t = 0; t < 18; ++t) { Wa[t] = Wa[t + 1]; Wb[t] = Wb[t + 1]; }
        Wa[18] = nW[u].x; Wb[18] = nW[u].y;
    }
    // ---- folded w_ll transpose (uniform per-block branch; 49 blocks) ----
    if (blockIdx.x < 49) {
        __shared__ float tile[64][65];
        int pos0 = blockIdx.x * 64;
        int lp = threadIdx.x & 63, g = threadIdx.x >> 6;
#pragma unroll
        for (int r = 0; r < 16; ++r) {
            int cc = r * 4 + g;
            tile[cc][lp] = wll[cc * (HS * WS) + pos0 + lp];
        }
        __syncthreads();
#pragma unroll
        for (int r = 0; r < 16; ++r) {
            int pl = r * 4 + g;
            wllT[(pos0 + pl) * CH + lp] = tile[lp][pl];
        }
    }
}

// ---- K2: FUSED column filters + q2c + MFMA mix (z=0: lo->P0, z=1: hi->P1,P2).
// Plane-pair products decompose along the z-split: z=0 produces planes
// {0,1,10,11} = s0,s5 (pr=0); z=1 produces planes {2..9} = s1..s4 (pr=1,2).
// sbT global tensor and the k_mix launch are eliminated.
// LDS: qTb 14.3KB (aliased by l1 in mix) + pA 16.1KB = 30.4KB -> 5 blocks/CU.
__global__ __launch_bounds__(256) void k_cols_mix(
    const unsigned short* __restrict__ lo_in,
    const unsigned short* __restrict__ hi_in, const float* __restrict__ wllT,
    const float* __restrict__ w1, const float* __restrict__ w2,
    const float* __restrict__ b1, const float* __restrict__ b2,
    unsigned short* __restrict__ xl, unsigned short* __restrict__ P0,
    unsigned short* __restrict__ P1, unsigned short* __restrict__ P2) {
    __shared__ __align__(16) unsigned short qTb[2][4][14][64];  // 14.3 KB
    __shared__ __align__(16) unsigned short pA[8][14][72];      // 16.1 KB
    // l1a/l1b (mix exchange) alias qTb (dead after q2c barrier)
    unsigned short (*l1a)[16][36] =
        reinterpret_cast<unsigned short(*)[16][36]>(&qTb[0][0][0][0]);
    unsigned short (*l1b)[16][36] = l1a + 4;

    int hf = blockIdx.y;
    int zmode = blockIdx.z;            // uniform branch
    int b = blockIdx.x / WH, wp = blockIdx.x % WH;
    int w0 = 2 * wp, tid = threadIdx.x;
    int q = tid >> 6, c = tid & 63;
    int rp = q >> 1, jc = q & 1;
    const unsigned short* srcp = zmode ? hi_in : lo_in;
    const unsigned short* colbase = srcp + (b * HS) * WS * CH + (w0 + jc) * CH + c;
    {
        int hstart = 2 * (hf * 14) + rp;
        float W[19];
#pragma unroll
        for (int t = 0; t < 19; ++t) W[t] = bf2f(colbase[symi(hstart - 9 + t) * (WS * CH)]);
        for (int rnd = 0; rnd < 2; ++rnd) {
            float nW0[7], nW1[7], nwll[7];
            int ii0 = rnd * 7;
#pragma unroll
            for (int u = 0; u < 7; ++u) {
                int h = hstart + 2 * (ii0 + u);
                nW0[u] = bf2f(colbase[symi(h + 10) * (WS * CH)]);
                nW1[u] = bf2f(colbase[symi(h + 11) * (WS * CH)]);
            }
            if (zmode == 0) {
#pragma unroll
                for (int u = 0; u < 7; ++u)
                    nwll[u] = wllT[((hstart + 2 * (ii0 + u)) * WS + (w0 + jc)) * CH + c];
            }
#pragma unroll
            for (int u = 0; u < 7; ++u) {
                int ii = ii0 + u;
                int h = hstart + 2 * ii;
                float v0 = 0.f, v1 = 0.f;
#pragma unroll
                for (int t = 0; t < 13; ++t) v0 += F_H0[t] * W[3 + t];
#pragma unroll
                for (int t = 0; t < 19; ++t) v1 += F_H1[t] * W[t];
                if (zmode == 0) {
                    xl[((b * HS + h) * WS + (w0 + jc)) * CH + c] = f2bf(v0 * nwll[u]);
                    qTb[0][q][ii][c] = f2bf(v1);
                } else {
                    qTb[0][q][ii][c] = f2bf(v0);   // hl
                    qTb[1][q][ii][c] = f2bf(v1);   // hh
                }
#pragma unroll
                for (int t = 0; t < 17; ++t) W[t] = W[t + 2];
                W[17] = nW0[u];
                W[18] = nW1[u];
            }
        }
    }
    __syncthreads();
    // fused q2c + bf16 pack into pA. Local plane maps:
    //   z=0: role -> local role (global 0,1,10,11)
    //   z=1: src0(hl) -> local 2+role (global 4..7);
    //        src1(hh) -> local role<2?role:4+role (global 2,3,8,9)
    {
        int qq = tid >> 5;                 // 0..7
        int role = qq & 3, half = qq >> 2; // ii 0..6 / 7..13
        int c0 = (tid & 31) * 2;
        int rowA = role & 1, rowB = 3 - (role & 1);
        float sgn = (role == 1 || role == 2) ? 1.f : -1.f;
        if (zmode == 0) {
#pragma unroll
            for (int g = 0; g < 7; ++g) {
                int ii = half * 7 + g;
                float2 av = bfp2(*(const unsigned*)&qTb[0][rowA][ii][c0]);
                float2 bv = bfp2(*(const unsigned*)&qTb[0][rowB][ii][c0]);
                float v0 = (av.x + sgn * bv.x) * ISQ2;
                float v1 = (av.y + sgn * bv.y) * ISQ2;
                *(unsigned*)&pA[role][ii][c0] = packbf(v0, v1);
            }
        } else {
#pragma unroll
            for (int src = 0; src < 2; ++src) {
                int pl = (src == 0) ? (2 + role) : ((role < 2) ? role : (4 + role));
#pragma unroll
                for (int g = 0; g < 7; ++g) {
                    int ii = half * 7 + g;
                    float2 av = bfp2(*(const unsigned*)&qTb[src][rowA][ii][c0]);
                    float2 bv = bfp2(*(const unsigned*)&qTb[src][rowB][ii][c0]);
                    float v0 = (av.x + sgn * bv.x) * ISQ2;
                    float v1 = (av.y + sgn * bv.y) * ISQ2;
                    *(unsigned*)&pA[pl][ii][c0] = packbf(v0, v1);
                }
            }
        }
    }
    __syncthreads();   // pA complete; qTb dead (l1a/l1b alias it)

    // ---- mix phase (weights loaded AFTER barrier to keep filter VGPR low)
    int lane = tid & 63;
    int wv = tid >> 6;
    int nb = __builtin_amdgcn_readfirstlane(wv);
    int quad = lane >> 4;
    int n = lane & 15;
    int rix = quad >> 1, dlo = (quad & 1) * 8;
    int chb = nb * 16 + dlo;
    int npos = (n < 14) ? n : 0;   // clamp: rows 14,15 discarded at store

    short8 B1r, B1i, B2r, B2i;
#pragma unroll
    for (int j = 0; j < 8; ++j) {
        int kk = quad * 8 + j;
        int riw = kk >> 4, dd = kk & 15;
        float v1r = w1[nb * 256 + dd * 16 + n];
        float v1i = w1[1024 + nb * 256 + dd * 16 + n];
        float v2r = w2[nb * 256 + dd * 16 + n];
        float v2i = w2[1024 + nb * 256 + dd * 16 + n];
        B1r[j] = (short)f2bf(riw ? -v1i : v1r);
        B1i[j] = (short)f2bf(riw ? v1r : v1i);
        B2r[j] = (short)f2bf(riw ? -v2i : v2r);
        B2i[j] = (short)f2bf(riw ? v2r : v2i);
    }
    float bias1r = b1[nb * 16 + n], bias1i = b1[64 + nb * 16 + n];
    float bias2r = b2[nb * 16 + n], bias2i = b2[64 + nb * 16 + n];

    auto mixprod = [&](int aP, int bP, unsigned short* __restrict__ Pd) {
        short8 A1a = *(const short8*)&pA[aP][npos][chb];
        short8 A1b = *(const short8*)&pA[bP][npos][chb];
        f32x4 a1r = {bias1r, bias1r, bias1r, bias1r};
        f32x4 a1i = {bias1i, bias1i, bias1i, bias1i};
        f32x4 b1r_ = a1r, b1i_ = a1i;
        a1r = __builtin_amdgcn_mfma_f32_16x16x32_bf16(A1a, B1r, a1r, 0, 0, 0);
        a1i = __builtin_amdgcn_mfma_f32_16x16x32_bf16(A1a, B1i, a1i, 0, 0, 0);
        b1r_ = __builtin_amdgcn_mfma_f32_16x16x32_bf16(A1b, B1r, b1r_, 0, 0, 0);
        b1i_ = __builtin_amdgcn_mfma_f32_16x16x32_bf16(A1b, B1i, b1i_, 0, 0, 0);
#pragma unroll
        for (int r = 0; r < 4; ++r) {
            int pos = quad * 4 + r;
            l1a[wv][pos][n] = f2bf(fmaxf(a1r[r], 0.f));
            l1a[wv][pos][16 + n] = f2bf(fmaxf(a1i[r], 0.f));
            l1b[wv][pos][n] = f2bf(fmaxf(b1r_[r], 0.f));
            l1b[wv][pos][16 + n] = f2bf(fmaxf(b1i_[r], 0.f));
        }
        union { short8 s8; uint2 u2[2]; } a2a, a2b;
        const unsigned short* rowpa = &l1a[wv][n][0];
        const unsigned short* rowpb = &l1b[wv][n][0];
        a2a.u2[0] = *(const uint2*)(rowpa + quad * 8);
        a2a.u2[1] = *(const uint2*)(rowpa + quad * 8 + 4);
        a2b.u2[0] = *(const uint2*)(rowpb + quad * 8);
        a2b.u2[1] = *(const uint2*)(rowpb + quad * 8 + 4);
        f32x4 aAr = {bias2r, bias2r, bias2r, bias2r};
        f32x4 aAi = {bias2i, bias2i, bias2i, bias2i};
        f32x4 aBr = aAr, aBi = aAi;
        aAr = __builtin_amdgcn_mfma_f32_16x16x32_bf16(a2a.s8, B2r, aAr, 0, 0, 0);
        aAi = __builtin_amdgcn_mfma_f32_16x16x32_bf16(a2a.s8, B2i, aAi, 0, 0, 0);
        aBr = __builtin_amdgcn_mfma_f32_16x16x32_bf16(a2b.s8, B2r, aBr, 0, 0, 0);
        aBi = __builtin_amdgcn_mfma_f32_16x16x32_bf16(a2b.s8, B2i, aBi, 0, 0, 0);
#pragma unroll
        for (int r = 0; r < 4; ++r) {
            int m = quad * 4 + r;
            if (m < 14) {
                int iig = hf * 14 + m;
                int o = ((b * HS + 2 * iig) * WS + 2 * wp) * CH + nb * 16 + n;
                Pd[o] = f2bf((aAr[r] + aBr[r]) * ISQ2);
                Pd[o + CH] = f2bf((aAi[r] + aBi[r]) * ISQ2);
                Pd[o + WS * CH] = f2bf((aAi[r] - aBi[r]) * ISQ2);
                Pd[o + WS * CH + CH] = f2bf((aBr[r] - aAr[r]) * ISQ2);
            }
        }
    };

    if (zmode == 0) {
        mixprod(rix, 2 + rix, P0);            // s0 x s5
    } else {
        mixprod(2 + rix, 4 + rix, P1);        // s2 x s3
        mixprod(rix, 6 + rix, P2);            // s1 x s4
    }
}

// ---- K4: inverse column pass, templated on mode (uniform blockIdx.z):
//   MODE=0: lo2 = G0col(xl bf16) + G1col(P0);  MODE=1: hi2 = G0col(P1) + G1col(P2)
// H-quarter split (blockIdx.y=4, 14 outputs) for occupancy (7 blocks/CU);
// 2-deep software-pipelined groups {4,4,4,2}. Outputs bf16.
template <int MODE>
__device__ __forceinline__ void inv_cols_body(
    const unsigned short* __restrict__ xl, const unsigned short* __restrict__ P0,
    const unsigned short* __restrict__ P1, const unsigned short* __restrict__ P2,
    unsigned short* __restrict__ lo2, unsigned short* __restrict__ hi2) {
    int hf = blockIdx.y;               // 0..3
    int b = blockIdx.x / 7, wg = blockIdx.x % 7;
    int wl = threadIdx.x >> 5, l = threadIdx.x & 31;
    int c0 = l * 2;
    int w = wg * 8 + wl;
    int base = (b * HS) * WS * CH + w * CH + c0;
    const int st = WS * CH;
    const unsigned short* Ap = (MODE == 0) ? xl : P1;
    const unsigned short* Bp = (MODE == 0) ? P0 : P2;
    unsigned short* outp = (MODE == 0) ? lo2 : hi2;
    auto ldA = [&](int r) -> float2 {
        return bfp2(*(const unsigned*)(Ap + base + r * st));
    };
    auto ldB = [&](int r) -> float2 {
        return bfp2(*(const unsigned*)(Bp + base + r * st));
    };
    int h0 = hf * 14;
    float Aa[19], Ab[19], Ba[13], Bb[13];
#pragma unroll
    for (int t = 0; t < 19; ++t) { float2 v = ldA(symi(h0 - 9 + t)); Aa[t] = v.x; Ab[t] = v.y; }
#pragma unroll
    for (int t = 0; t < 13; ++t) { float2 v = ldB(symi(h0 - 6 + t)); Ba[t] = v.x; Bb[t] = v.y; }
    float2 pa0[4], pb0[4], pa1[4], pb1[4];
#define LDG(bA, bB, OFF, CNT)                                                   \
    {                                                                           \
        _Pragma("unroll") for (int u = 0; u < (CNT); ++u)                       \
            bA[u] = ldA(symi(h0 + (OFF) + u + 10));                             \
        _Pragma("unroll") for (int u = 0; u < (CNT); ++u)                       \
            bB[u] = ldB(symi(h0 + (OFF) + u + 7));                              \
    }
#define CPG(bA, bB, OFF, CNT)                                                   \
    {                                                                           \
        _Pragma("unroll") for (int u = 0; u < (CNT); ++u) {                     \
            int h = h0 + (OFF) + u;                                             \
            float acca = 0.f, accb = 0.f;                                       \
            _Pragma("unroll") for (int t = 0; t < 19; ++t) {                    \
                acca += F_G0[t] * Aa[t]; accb += F_G0[t] * Ab[t];               \
            }                                                                   \
            _Pragma("unroll") for (int t = 0; t < 13; ++t) {                    \
                acca += F_G1[t] * Ba[t]; accb += F_G1[t] * Bb[t];               \
            }                                                                   \
            *(unsigned*)(outp + base + h * st) = packbf(acca, accb);            \
            _Pragma("unroll") for (int t = 0; t < 18; ++t) {                    \
                Aa[t] = Aa[t + 1]; Ab[t] = Ab[t + 1];                           \
            }                                                                   \
            _Pragma("unroll") for (int t = 0; t < 12; ++t) {                    \
                Ba[t] = Ba[t + 1]; Bb[t] = Bb[t + 1];                           \
            }                                                                   \
            Aa[18] = bA[u].x; Ab[18] = bA[u].y;                                 \
            Ba[12] = bB[u].x; Bb[12] = bB[u].y;                                 \
        }                                                                       \
    }
    LDG(pa0, pb0, 0, 4) LDG(pa1, pb1, 4, 4)
    CPG(pa0, pb0, 0, 4) LDG(pa0, pb0, 8, 4)
    CPG(pa1, pb1, 4, 4) LDG(pa1, pb1, 12, 2)
    CPG(pa0, pb0, 8, 4)
    CPG(pa1, pb1, 12, 2)
#undef LDG
#undef CPG
}

__global__ __launch_bounds__(256) void k_inv_cols(
    const unsigned short* __restrict__ xl, const unsigned short* __restrict__ P0,
    const unsigned short* __restrict__ P1, const unsigned short* __restrict__ P2,
    unsigned short* __restrict__ lo2, unsigned short* __restrict__ hi2) {
    if (blockIdx.z == 0)
        inv_cols_body<0>(xl, P0, P1, P2, lo2, hi2);
    else
        inv_cols_body<1>(xl, P0, P1, P2, lo2, hi2);
}

// ---- K5: inverse row filters (bf16 in) -> out (fp32), 2ch/thread, batched
__global__ __launch_bounds__(256) void k_inv_rows(
    const unsigned short* __restrict__ lo2,
    const unsigned short* __restrict__ hi2, float* __restrict__ out) {
    int b = blockIdx.x / HS, h = blockIdx.x % HS;
    int strip = threadIdx.x >> 5;        // 0..7 strips of 7 w
    int c0 = (threadIdx.x & 31) * 2;
    int base = (b * HS + h) * WS * CH + c0;
    const unsigned short* rlo = lo2 + base;
    const unsigned short* rhi = hi2 + base;
    float* op = out + base;
    int w0s = strip * 7;
    float Aa[19], Ab[19], Ba[13], Bb[13];
#pragma unroll
    for (int t = 0; t < 19; ++t) {
        float2 v = bfp2(*(const unsigned*)(rlo + symi(w0s - 9 + t) * CH));
        Aa[t] = v.x; Ab[t] = v.y;
    }
#pragma unroll
    for (int t = 0; t < 13; ++t) {
        float2 v = bfp2(*(const unsigned*)(rhi + symi(w0s - 6 + t) * CH));
        Ba[t] = v.x; Bb[t] = v.y;
    }
    float2 nA[7], nB[7];
#pragma unroll
    for (int u = 0; u < 7; ++u) nA[u] = bfp2(*(const unsigned*)(rlo + symi(w0s + u + 10) * CH));
#pragma unroll
    for (int u = 0; u < 7; ++u) nB[u] = bfp2(*(const unsigned*)(rhi + symi(w0s + u + 7) * CH));
#pragma unroll
    for (int u = 0; u < 7; ++u) {
        int w = w0s + u;
        float acca = 0.f, accb = 0.f;
#pragma unroll
        for (int t = 0; t < 19; ++t) { acca += F_G0[t] * Aa[t]; accb += F_G0[t] * Ab[t]; }
#pragma unroll
        for (int t = 0; t < 13; ++t) { acca += F_G1[t] * Ba[t]; accb += F_G1[t] * Bb[t]; }
        float2 ov; ov.x = acca; ov.y = accb;
        *(float2*)(op + w * CH) = ov;
#pragma unroll
        for (int t = 0; t < 18; ++t) { Aa[t] = Aa[t + 1]; Ab[t] = Ab[t + 1]; }
#pragma unroll
        for (int t = 0; t < 12; ++t) { Ba[t] = Ba[t + 1]; Bb[t] = Bb[t + 1]; }
        Aa[18] = nA[u].x; Ab[18] = nA[u].y;
        Ba[12] = nB[u].x; Bb[12] = nB[u].y;
    }
}

extern "C" void kernel_launch(void* const* d_in, const int* in_sizes, int n_in,
                              void* d_out, int out_size, void* d_ws, size_t ws_size,
                              hipStream_t stream) {
    const float* x = (const float*)d_in[0];
    const float* w_ll = (const float*)d_in[1];
    const float* w1 = (const float*)d_in[2];
    const float* w2 = (const float*)d_in[3];
    const float* b1 = (const float*)d_in[4];
    const float* b2 = (const float*)d_in[5];
    float* out = (float*)d_out;

    // workspace map (float units). A = 6,422,528; SBf = 9,633,792.
    // xl(bf16, region A) | lo2 bf16 (old sbT region) | hi2 bf16 | lo_in | hi_in
    // | P0 | P1 | P2   (sbT eliminated by the k_cols_mix fusion)
    const size_t A = (size_t)BT * HS * WS * CH;
    const size_t SBf = (size_t)12 * 64 * BT * PPOS / 2;
    float* wsf = (float*)d_ws;
    unsigned short* xl = (unsigned short*)wsf;          // bf16 (region oversized)
    unsigned short* lo2 = (unsigned short*)(wsf + A);
    unsigned short* hi2 = (unsigned short*)(wsf + A + SBf);
    unsigned short* lo_in = (unsigned short*)(wsf + A + SBf + A);
    unsigned short* hi_in = lo_in + A;                  // bf16
    unsigned short* P0 = hi_in + A;                     // bf16
    unsigned short* P1 = P0 + A;
    unsigned short* P2 = P1 + A;

    float* wllT = out;  // staged in d_out head (overwritten by k_inv_rows)

    k_fwd_rows<<<BT * HS, 256, 0, stream>>>(x, lo_in, hi_in, w_ll, wllT);
    k_cols_mix<<<dim3(BT * WH, 2, 2), 256, 0, stream>>>(lo_in, hi_in, wllT, w1,
                                                        w2, b1, b2, xl, P0, P1, P2);
    k_inv_cols<<<dim3(BT * 7, 4, 2), 256, 0, stream>>>(xl, P0, P1, P2, lo2, hi2);
    k_inv_rows<<<BT * HS, 256, 0, stream>>>(lo2, hi2, out);
}

// Round 12
// 149.905 us; speedup vs baseline: 1.1285x; 1.0860x over previous
//
#include <hip/hip_runtime.h>

#define BT 32
#define CH 64
#define HS 56
#define WS 56
#define HH 28
#define WH 28

// ---------------- filter constants (exact reference values) ----------------
namespace {
constexpr float ISQ2 = 0.70710678118654752440f;
constexpr float F_H0[13] = {-0.0017578125f, 0.0f, 0.022265625f, -0.046875f,
    -0.0482421875f, 0.296875f, 0.55546875f, 0.296875f, -0.0482421875f,
    -0.046875f, 0.022265625f, 0.0f, -0.0017578125f};
constexpr float F_H1[19] = {-7.0626e-05f, 0.0f, 0.00134189f, -0.00188341f,
    -0.0071566f, 0.023856f, 0.0556431f, -0.0516881f, -0.299758f, 0.559431f,
    -0.299758f, -0.0516881f, 0.0556431f, 0.023856f, -0.0071566f,
    -0.00188341f, 0.00134189f, 0.0f, -7.0626e-05f};
constexpr float F_G0[19] = {7.0626e-05f, 0.0f, -0.00134189f, -0.00188341f,
    0.0071566f, 0.023856f, -0.0556431f, -0.0516881f, 0.299758f, 0.559431f,
    0.299758f, -0.0516881f, -0.0556431f, 0.023856f, 0.0071566f,
    -0.00188341f, -0.00134189f, 0.0f, 7.0626e-05f};
constexpr float F_G1[13] = {-0.0017578125f, 0.0f, 0.022265625f, 0.046875f,
    -0.0482421875f, -0.296875f, 0.55546875f, -0.296875f, -0.0482421875f,
    0.046875f, 0.022265625f, 0.0f, -0.0017578125f};
}

__device__ __forceinline__ int symi(int k) {
    k = (k < 0) ? (-1 - k) : k;
    k = (k >= HS) ? (2 * HS - 1 - k) : k;
    return k;
}
__device__ __forceinline__ int symi_lo(int k) { return (k < 0) ? (-1 - k) : k; }
__device__ __forceinline__ int symi_hi(int k) { return (k >= HS) ? (2 * HS - 1 - k) : k; }

__device__ __forceinline__ unsigned short f2bf(float f) {  // RNE bf16
    unsigned u = __float_as_uint(f);
    u += 0x7fffu + ((u >> 16) & 1u);
    return (unsigned short)(u >> 16);
}
__device__ __forceinline__ float bf2f(unsigned short h) {
    return __uint_as_float(((unsigned)h) << 16);
}
// HW packed f32->bf16 RNE (bit-identical to f2bf for finite values)
__device__ __forceinline__ unsigned cvtpk(float lo, float hi) {
    unsigned r;
    asm("v_cvt_pk_bf16_f32 %0, %1, %2" : "=v"(r) : "v"(lo), "v"(hi));
    return r;
}
// unpack 2 packed bf16 (channels c0, c0+1) from one dword
__device__ __forceinline__ float2 bfp2(unsigned u) {
    float2 r;
    r.x = __uint_as_float((u & 0xffffu) << 16);
    r.y = __uint_as_float(u & 0xffff0000u);
    return r;
}
__device__ __forceinline__ unsigned packbf(float a, float b) {
    return (unsigned)f2bf(a) | ((unsigned)f2bf(b) << 16);
}

typedef __attribute__((ext_vector_type(8))) short short8;  // 8 bf16 (4 VGPR)
typedef __attribute__((ext_vector_type(4))) float f32x4;

#define PPOS 784

// ---- K1: forward row filters: x -> lo, hi (bf16).
// Block 0..48: also transpose w_ll -> wllT. Block 49: also precompute bf16
// MFMA weight fragments wB[4][256][8] (B1r,B1i,B2r,B2i per (nb,lane)).
__global__ __launch_bounds__(256) void k_fwd_rows(const float* __restrict__ x,
                                                  unsigned short* __restrict__ lo,
                                                  unsigned short* __restrict__ hi,
                                                  const float* __restrict__ wll,
                                                  float* __restrict__ wllT,
                                                  const float* __restrict__ w1,
                                                  const float* __restrict__ w2,
                                                  unsigned short* __restrict__ wB) {
    int b = blockIdx.x / HS, h = blockIdx.x % HS;
    int strip = threadIdx.x >> 5;        // 0..7 strips of 7 w
    int c0 = (threadIdx.x & 31) * 2;
    int base = (b * HS + h) * WS * CH + c0;
    const float* row = x + base;
    unsigned short* lop = lo + base;
    unsigned short* hip = hi + base;
    int w0s = strip * 7;
    float Wa[19], Wb[19];
#pragma unroll
    for (int t = 0; t < 19; ++t) {
        float2 v = *(const float2*)(row + symi(w0s - 9 + t) * CH);
        Wa[t] = v.x; Wb[t] = v.y;
    }
    float2 nW[7];
#pragma unroll
    for (int u = 0; u < 7; ++u) nW[u] = *(const float2*)(row + symi(w0s + u + 10) * CH);
#pragma unroll
    for (int u = 0; u < 7; ++u) {
        int w = w0s + u;
        float aLo = 0.f, aHi = 0.f, bLo = 0.f, bHi = 0.f;
#pragma unroll
        for (int t = 0; t < 13; ++t) { aLo += F_H0[t] * Wa[3 + t]; bLo += F_H0[t] * Wb[3 + t]; }
#pragma unroll
        for (int t = 0; t < 19; ++t) { aHi += F_H1[t] * Wa[t]; bHi += F_H1[t] * Wb[t]; }
        *(unsigned*)(lop + w * CH) = packbf(aLo, bLo);
        *(unsigned*)(hip + w * CH) = packbf(aHi, bHi);
#pragma unroll
        for (int t = 0; t < 18; ++t) { Wa[t] = Wa[t + 1]; Wb[t] = Wb[t + 1]; }
        Wa[18] = nW[u].x; Wb[18] = nW[u].y;
    }
    // ---- folded w_ll transpose (uniform per-block branch; 49 blocks) ----
    if (blockIdx.x < 49) {
        __shared__ float tile[64][65];
        int pos0 = blockIdx.x * 64;
        int lp = threadIdx.x & 63, g = threadIdx.x >> 6;
#pragma unroll
        for (int r = 0; r < 16; ++r) {
            int cc = r * 4 + g;
            tile[cc][lp] = wll[cc * (HS * WS) + pos0 + lp];
        }
        __syncthreads();
#pragma unroll
        for (int r = 0; r < 16; ++r) {
            int pl = r * 4 + g;
            wllT[(pos0 + pl) * CH + lp] = tile[lp][pl];
        }
    } else if (blockIdx.x == 49) {
        // ---- weight fragment precompute (bit-identical to old in-kernel) ---
        int tid = threadIdx.x;
        int lane = tid & 63;
        int nb = tid >> 6;
        int quad = lane >> 4, n = lane & 15;
        short8 B1r, B1i, B2r, B2i;
#pragma unroll
        for (int j = 0; j < 8; ++j) {
            int kk = quad * 8 + j;
            int riw = kk >> 4, dd = kk & 15;
            float v1r = w1[nb * 256 + dd * 16 + n];
            float v1i = w1[1024 + nb * 256 + dd * 16 + n];
            float v2r = w2[nb * 256 + dd * 16 + n];
            float v2i = w2[1024 + nb * 256 + dd * 16 + n];
            B1r[j] = (short)f2bf(riw ? -v1i : v1r);
            B1i[j] = (short)f2bf(riw ? v1r : v1i);
            B2r[j] = (short)f2bf(riw ? -v2i : v2r);
            B2i[j] = (short)f2bf(riw ? v2r : v2i);
        }
        *(short8*)(wB + (0 * 256 + tid) * 8) = B1r;
        *(short8*)(wB + (1 * 256 + tid) * 8) = B1i;
        *(short8*)(wB + (2 * 256 + tid) * 8) = B2r;
        *(short8*)(wB + (3 * 256 + tid) * 8) = B2i;
    }
}

// ---- K2: FUSED column filters + q2c + MFMA mix, templated on (ZM, HF).
// ZM=0: lo->P0 (planes s0,s5); ZM=1: hi->P1,P2 (s2,s3 / s1,s4).
// HF specialization makes reflection one-sided (several groups reflection-free).
// Ring-buffer window (compile-time %19) removes shift movs; cvt_pk_bf16_f32
// replaces f2bf pairs; weight fragments loaded from precomputed wB.
template <int ZM, int HF>
__device__ __forceinline__ void cols_mix_body(
    unsigned short (&qTb)[2][4][14][64], unsigned short (&pA)[8][14][72],
    const unsigned short* __restrict__ lo_in,
    const unsigned short* __restrict__ hi_in, const float* __restrict__ wllT,
    const unsigned short* __restrict__ wB, const float* __restrict__ b1,
    const float* __restrict__ b2, unsigned short* __restrict__ xl,
    unsigned short* __restrict__ P0, unsigned short* __restrict__ P1,
    unsigned short* __restrict__ P2) {
    unsigned short (*l1a)[16][36] =
        reinterpret_cast<unsigned short(*)[16][36]>(&qTb[0][0][0][0]);
    unsigned short (*l1b)[16][36] = l1a + 4;

    int b = blockIdx.x / WH, wp = blockIdx.x % WH;
    int w0 = 2 * wp, tid = threadIdx.x;
    int q = tid >> 6, c = tid & 63;
    int rp = q >> 1, jc = q & 1;
    const unsigned short* srcp = ZM ? hi_in : lo_in;
    const unsigned short* colbase = srcp + (b * HS) * WS * CH + (w0 + jc) * CH + c;
    {
        int hstart = HF * 28 + rp;
        float W[19];
#pragma unroll
        for (int t = 0; t < 19; ++t) {
            int r = (HF == 0) ? symi_lo(hstart - 9 + t) : (hstart - 9 + t);
            W[t] = bf2f(colbase[r * (WS * CH)]);
        }
#pragma unroll
        for (int rnd = 0; rnd < 2; ++rnd) {
            float nW0[7], nW1[7], nwll[7];
            int ii0 = rnd * 7;
#pragma unroll
            for (int u = 0; u < 7; ++u) {
                int h = hstart + 2 * (ii0 + u);
                int r0 = (HF == 0) ? (h + 10) : symi_hi(h + 10);
                int r1 = (HF == 0) ? (h + 11) : symi_hi(h + 11);
                nW0[u] = bf2f(colbase[r0 * (WS * CH)]);
                nW1[u] = bf2f(colbase[r1 * (WS * CH)]);
            }
            if (ZM == 0) {
#pragma unroll
                for (int u = 0; u < 7; ++u)
                    nwll[u] = wllT[((hstart + 2 * (ii0 + u)) * WS + (w0 + jc)) * CH + c];
            }
#pragma unroll
            for (int u = 0; u < 7; ++u) {
                const int ii = ii0 + u;
                int h = hstart + 2 * ii;
                float v0 = 0.f, v1 = 0.f;
#pragma unroll
                for (int t = 0; t < 13; ++t) v0 += F_H0[t] * W[(2 * ii + 3 + t) % 19];
#pragma unroll
                for (int t = 0; t < 19; ++t) v1 += F_H1[t] * W[(2 * ii + t) % 19];
                if (ZM == 0) {
                    unsigned pk = cvtpk(v0 * nwll[u], v1);
                    xl[((b * HS + h) * WS + (w0 + jc)) * CH + c] = (unsigned short)pk;
                    qTb[0][q][ii][c] = (unsigned short)(pk >> 16);
                } else {
                    unsigned pk = cvtpk(v0, v1);
                    qTb[0][q][ii][c] = (unsigned short)pk;          // hl
                    qTb[1][q][ii][c] = (unsigned short)(pk >> 16);  // hh
                }
                W[(2 * ii) % 19] = nW0[u];
                W[(2 * ii + 1) % 19] = nW1[u];
            }
        }
    }
    __syncthreads();
    // fused q2c + bf16 pack into pA. Local plane maps:
    //   ZM=0: role -> local role (global 0,1,10,11)
    //   ZM=1: src0(hl) -> local 2+role (global 4..7);
    //         src1(hh) -> local role<2?role:4+role (global 2,3,8,9)
    {
        int qq = tid >> 5;                 // 0..7
        int role = qq & 3, half = qq >> 2; // ii 0..6 / 7..13
        int c0 = (tid & 31) * 2;
        int rowA = role & 1, rowB = 3 - (role & 1);
        float sgn = (role == 1 || role == 2) ? 1.f : -1.f;
        if (ZM == 0) {
#pragma unroll
            for (int g = 0; g < 7; ++g) {
                int ii = half * 7 + g;
                float2 av = bfp2(*(const unsigned*)&qTb[0][rowA][ii][c0]);
                float2 bv = bfp2(*(const unsigned*)&qTb[0][rowB][ii][c0]);
                *(unsigned*)&pA[role][ii][c0] =
                    cvtpk((av.x + sgn * bv.x) * ISQ2, (av.y + sgn * bv.y) * ISQ2);
            }
        } else {
#pragma unroll
            for (int src = 0; src < 2; ++src) {
                int pl = (src == 0) ? (2 + role) : ((role < 2) ? role : (4 + role));
#pragma unroll
                for (int g = 0; g < 7; ++g) {
                    int ii = half * 7 + g;
                    float2 av = bfp2(*(const unsigned*)&qTb[src][rowA][ii][c0]);
                    float2 bv = bfp2(*(const unsigned*)&qTb[src][rowB][ii][c0]);
                    *(unsigned*)&pA[pl][ii][c0] =
                        cvtpk((av.x + sgn * bv.x) * ISQ2, (av.y + sgn * bv.y) * ISQ2);
                }
            }
        }
    }
    __syncthreads();   // pA complete; qTb dead (l1a/l1b alias it)

    // ---- mix phase: weight fragments from precomputed wB (4x dwordx4)
    int lane = tid & 63;
    int wv = tid >> 6;
    int nb = __builtin_amdgcn_readfirstlane(wv);
    int quad = lane >> 4;
    int n = lane & 15;
    int rix = quad >> 1, dlo = (quad & 1) * 8;
    int chb = nb * 16 + dlo;
    int npos = (n < 14) ? n : 0;   // clamp: rows 14,15 discarded at store

    short8 B1r = *(const short8*)(wB + (0 * 256 + tid) * 8);
    short8 B1i = *(const short8*)(wB + (1 * 256 + tid) * 8);
    short8 B2r = *(const short8*)(wB + (2 * 256 + tid) * 8);
    short8 B2i = *(const short8*)(wB + (3 * 256 + tid) * 8);
    float bias1r = b1[nb * 16 + n], bias1i = b1[64 + nb * 16 + n];
    float bias2r = b2[nb * 16 + n], bias2i = b2[64 + nb * 16 + n];

    auto mixprod = [&](int aP, int bP, unsigned short* __restrict__ Pd) {
        short8 A1a = *(const short8*)&pA[aP][npos][chb];
        short8 A1b = *(const short8*)&pA[bP][npos][chb];
        f32x4 a1r = {bias1r, bias1r, bias1r, bias1r};
        f32x4 a1i = {bias1i, bias1i, bias1i, bias1i};
        f32x4 b1r_ = a1r, b1i_ = a1i;
        a1r = __builtin_amdgcn_mfma_f32_16x16x32_bf16(A1a, B1r, a1r, 0, 0, 0);
        a1i = __builtin_amdgcn_mfma_f32_16x16x32_bf16(A1a, B1i, a1i, 0, 0, 0);
        b1r_ = __builtin_amdgcn_mfma_f32_16x16x32_bf16(A1b, B1r, b1r_, 0, 0, 0);
        b1i_ = __builtin_amdgcn_mfma_f32_16x16x32_bf16(A1b, B1i, b1i_, 0, 0, 0);
#pragma unroll
        for (int r = 0; r < 4; ++r) {
            int pos = quad * 4 + r;
            unsigned pka = cvtpk(fmaxf(a1r[r], 0.f), fmaxf(a1i[r], 0.f));
            unsigned pkb = cvtpk(fmaxf(b1r_[r], 0.f), fmaxf(b1i_[r], 0.f));
            l1a[wv][pos][n] = (unsigned short)pka;
            l1a[wv][pos][16 + n] = (unsigned short)(pka >> 16);
            l1b[wv][pos][n] = (unsigned short)pkb;
            l1b[wv][pos][16 + n] = (unsigned short)(pkb >> 16);
        }
        union { short8 s8; uint2 u2[2]; } a2a, a2b;
        const unsigned short* rowpa = &l1a[wv][n][0];
        const unsigned short* rowpb = &l1b[wv][n][0];
        a2a.u2[0] = *(const uint2*)(rowpa + quad * 8);
        a2a.u2[1] = *(const uint2*)(rowpa + quad * 8 + 4);
        a2b.u2[0] = *(const uint2*)(rowpb + quad * 8);
        a2b.u2[1] = *(const uint2*)(rowpb + quad * 8 + 4);
        f32x4 aAr = {bias2r, bias2r, bias2r, bias2r};
        f32x4 aAi = {bias2i, bias2i, bias2i, bias2i};
        f32x4 aBr = aAr, aBi = aAi;
        aAr = __builtin_amdgcn_mfma_f32_16x16x32_bf16(a2a.s8, B2r, aAr, 0, 0, 0);
        aAi = __builtin_amdgcn_mfma_f32_16x16x32_bf16(a2a.s8, B2i, aAi, 0, 0, 0);
        aBr = __builtin_amdgcn_mfma_f32_16x16x32_bf16(a2b.s8, B2r, aBr, 0, 0, 0);
        aBi = __builtin_amdgcn_mfma_f32_16x16x32_bf16(a2b.s8, B2i, aBi, 0, 0, 0);
#pragma unroll
        for (int r = 0; r < 4; ++r) {
            int m = quad * 4 + r;
            if (m < 14) {
                int iig = HF * 14 + m;
                int o = ((b * HS + 2 * iig) * WS + 2 * wp) * CH + nb * 16 + n;
                unsigned pk0 = cvtpk((aAr[r] + aBr[r]) * ISQ2, (aAi[r] + aBi[r]) * ISQ2);
                unsigned pk1 = cvtpk((aAi[r] - aBi[r]) * ISQ2, (aBr[r] - aAr[r]) * ISQ2);
                Pd[o] = (unsigned short)pk0;
                Pd[o + CH] = (unsigned short)(pk0 >> 16);
                Pd[o + WS * CH] = (unsigned short)pk1;
                Pd[o + WS * CH + CH] = (unsigned short)(pk1 >> 16);
            }
        }
    };

    if (ZM == 0) {
        mixprod(rix, 2 + rix, P0);            // s0 x s5
    } else {
        mixprod(2 + rix, 4 + rix, P1);        // s2 x s3
        mixprod(rix, 6 + rix, P2);            // s1 x s4
    }
}

__global__ __launch_bounds__(256) void k_cols_mix(
    const unsigned short* __restrict__ lo_in,
    const unsigned short* __restrict__ hi_in, const float* __restrict__ wllT,
    const unsigned short* __restrict__ wB, const float* __restrict__ b1,
    const float* __restrict__ b2, unsigned short* __restrict__ xl,
    unsigned short* __restrict__ P0, unsigned short* __restrict__ P1,
    unsigned short* __restrict__ P2) {
    __shared__ __align__(16) unsigned short qTb[2][4][14][64];  // 14.3 KB
    __shared__ __align__(16) unsigned short pA[8][14][72];      // 16.1 KB
    if (blockIdx.z == 0) {
        if (blockIdx.y == 0)
            cols_mix_body<0, 0>(qTb, pA, lo_in, hi_in, wllT, wB, b1, b2, xl, P0, P1, P2);
        else
            cols_mix_body<0, 1>(qTb, pA, lo_in, hi_in, wllT, wB, b1, b2, xl, P0, P1, P2);
    } else {
        if (blockIdx.y == 0)
            cols_mix_body<1, 0>(qTb, pA, lo_in, hi_in, wllT, wB, b1, b2, xl, P0, P1, P2);
        else
            cols_mix_body<1, 1>(qTb, pA, lo_in, hi_in, wllT, wB, b1, b2, xl, P0, P1, P2);
    }
}

// ---- K4: inverse column pass, templated on mode (uniform blockIdx.z):
//   MODE=0: lo2 = G0col(xl bf16) + G1col(P0);  MODE=1: hi2 = G0col(P1) + G1col(P2)
// H-quarter split (blockIdx.y=4, 14 outputs) for occupancy (7 blocks/CU);
// 2-deep software-pipelined groups {4,4,4,2}. Outputs bf16.
template <int MODE>
__device__ __forceinline__ void inv_cols_body(
    const unsigned short* __restrict__ xl, const unsigned short* __restrict__ P0,
    const unsigned short* __restrict__ P1, const unsigned short* __restrict__ P2,
    unsigned short* __restrict__ lo2, unsigned short* __restrict__ hi2) {
    int hf = blockIdx.y;               // 0..3
    int b = blockIdx.x / 7, wg = blockIdx.x % 7;
    int wl = threadIdx.x >> 5, l = threadIdx.x & 31;
    int c0 = l * 2;
    int w = wg * 8 + wl;
    int base = (b * HS) * WS * CH + w * CH + c0;
    const int st = WS * CH;
    const unsigned short* Ap = (MODE == 0) ? xl : P1;
    const unsigned short* Bp = (MODE == 0) ? P0 : P2;
    unsigned short* outp = (MODE == 0) ? lo2 : hi2;
    auto ldA = [&](int r) -> float2 {
        return bfp2(*(const unsigned*)(Ap + base + r * st));
    };
    auto ldB = [&](int r) -> float2 {
        return bfp2(*(const unsigned*)(Bp + base + r * st));
    };
    int h0 = hf * 14;
    float Aa[19], Ab[19], Ba[13], Bb[13];
#pragma unroll
    for (int t = 0; t < 19; ++t) { float2 v = ldA(symi(h0 - 9 + t)); Aa[t] = v.x; Ab[t] = v.y; }
#pragma unroll
    for (int t = 0; t < 13; ++t) { float2 v = ldB(symi(h0 - 6 + t)); Ba[t] = v.x; Bb[t] = v.y; }
    float2 pa0[4], pb0[4], pa1[4], pb1[4];
#define LDG(bA, bB, OFF, CNT)                                                   \
    {                                                                           \
        _Pragma("unroll") for (int u = 0; u < (CNT); ++u)                       \
            bA[u] = ldA(symi(h0 + (OFF) + u + 10));                             \
        _Pragma("unroll") for (int u = 0; u < (CNT); ++u)                       \
            bB[u] = ldB(symi(h0 + (OFF) + u + 7));                              \
    }
#define CPG(bA, bB, OFF, CNT)                                                   \
    {                                                                           \
        _Pragma("unroll") for (int u = 0; u < (CNT); ++u) {                     \
            int h = h0 + (OFF) + u;                                             \
            float acca = 0.f, accb = 0.f;                                       \
            _Pragma("unroll") for (int t = 0; t < 19; ++t) {                    \
                acca += F_G0[t] * Aa[t]; accb += F_G0[t] * Ab[t];               \
            }                                                                   \
            _Pragma("unroll") for (int t = 0; t < 13; ++t) {                    \
                acca += F_G1[t] * Ba[t]; accb += F_G1[t] * Bb[t];               \
            }                                                                   \
            *(unsigned*)(outp + base + h * st) = packbf(acca, accb);            \
            _Pragma("unroll") for (int t = 0; t < 18; ++t) {                    \
                Aa[t] = Aa[t + 1]; Ab[t] = Ab[t + 1];                           \
            }                                                                   \
            _Pragma("unroll") for (int t = 0; t < 12; ++t) {                    \
                Ba[t] = Ba[t + 1]; Bb[t] = Bb[t + 1];                           \
            }                                                                   \
            Aa[18] = bA[u].x; Ab[18] = bA[u].y;                                 \
            Ba[12] = bB[u].x; Bb[12] = bB[u].y;                                 \
        }                                                                       \
    }
    LDG(pa0, pb0, 0, 4) LDG(pa1, pb1, 4, 4)
    CPG(pa0, pb0, 0, 4) LDG(pa0, pb0, 8, 4)
    CPG(pa1, pb1, 4, 4) LDG(pa1, pb1, 12, 2)
    CPG(pa0, pb0, 8, 4)
    CPG(pa1, pb1, 12, 2)
#undef LDG
#undef CPG
}

__global__ __launch_bounds__(256) void k_inv_cols(
    const unsigned short* __restrict__ xl, const unsigned short* __restrict__ P0,
    const unsigned short* __restrict__ P1, const unsigned short* __restrict__ P2,
    unsigned short* __restrict__ lo2, unsigned short* __restrict__ hi2) {
    if (blockIdx.z == 0)
        inv_cols_body<0>(xl, P0, P1, P2, lo2, hi2);
    else
        inv_cols_body<1>(xl, P0, P1, P2, lo2, hi2);
}

// ---- K5: inverse row filters (bf16 in) -> out (fp32), 2ch/thread, batched
__global__ __launch_bounds__(256) void k_inv_rows(
    const unsigned short* __restrict__ lo2,
    const unsigned short* __restrict__ hi2, float* __restrict__ out) {
    int b = blockIdx.x / HS, h = blockIdx.x % HS;
    int strip = threadIdx.x >> 5;        // 0..7 strips of 7 w
    int c0 = (threadIdx.x & 31) * 2;
    int base = (b * HS + h) * WS * CH + c0;
    const unsigned short* rlo = lo2 + base;
    const unsigned short* rhi = hi2 + base;
    float* op = out + base;
    int w0s = strip * 7;
    float Aa[19], Ab[19], Ba[13], Bb[13];
#pragma unroll
    for (int t = 0; t < 19; ++t) {
        float2 v = bfp2(*(const unsigned*)(rlo + symi(w0s - 9 + t) * CH));
        Aa[t] = v.x; Ab[t] = v.y;
    }
#pragma unroll
    for (int t = 0; t < 13; ++t) {
        float2 v = bfp2(*(const unsigned*)(rhi + symi(w0s - 6 + t) * CH));
        Ba[t] = v.x; Bb[t] = v.y;
    }
    float2 nA[7], nB[7];
#pragma unroll
    for (int u = 0; u < 7; ++u) nA[u] = bfp2(*(const unsigned*)(rlo + symi(w0s + u + 10) * CH));
#pragma unroll
    for (int u = 0; u < 7; ++u) nB[u] = bfp2(*(const unsigned*)(rhi + symi(w0s + u + 7) * CH));
#pragma unroll
    for (int u = 0; u < 7; ++u) {
        int w = w0s + u;
        float acca = 0.f, accb = 0.f;
#pragma unroll
        for (int t = 0; t < 19; ++t) { acca += F_G0[t] * Aa[t]; accb += F_G0[t] * Ab[t]; }
#pragma unroll
        for (int t = 0; t < 13; ++t) { acca += F_G1[t] * Ba[t]; accb += F_G1[t] * Bb[t]; }
        float2 ov; ov.x = acca; ov.y = accb;
        *(float2*)(op + w * CH) = ov;
#pragma unroll
        for (int t = 0; t < 18; ++t) { Aa[t] = Aa[t + 1]; Ab[t] = Ab[t + 1]; }
#pragma unroll
        for (int t = 0; t < 12; ++t) { Ba[t] = Ba[t + 1]; Bb[t] = Bb[t + 1]; }
        Aa[18] = nA[u].x; Ab[18] = nA[u].y;
        Ba[12] = nB[u].x; Bb[12] = nB[u].y;
    }
}

extern "C" void kernel_launch(void* const* d_in, const int* in_sizes, int n_in,
                              void* d_out, int out_size, void* d_ws, size_t ws_size,
                              hipStream_t stream) {
    const float* x = (const float*)d_in[0];
    const float* w_ll = (const float*)d_in[1];
    const float* w1 = (const float*)d_in[2];
    const float* w2 = (const float*)d_in[3];
    const float* b1 = (const float*)d_in[4];
    const float* b2 = (const float*)d_in[5];
    float* out = (float*)d_out;

    // workspace map (float units). A = 6,422,528; SBf = 9,633,792.
    // xl(bf16, region A) | lo2 bf16 (SBf region) | hi2 bf16 (A/2) | wB (gap)
    // | lo_in | hi_in | P0 | P1 | P2
    const size_t A = (size_t)BT * HS * WS * CH;
    const size_t SBf = (size_t)12 * 64 * BT * PPOS / 2;
    float* wsf = (float*)d_ws;
    unsigned short* xl = (unsigned short*)wsf;          // bf16 (region oversized)
    unsigned short* lo2 = (unsigned short*)(wsf + A);
    unsigned short* hi2 = (unsigned short*)(wsf + A + SBf);
    unsigned short* wB = (unsigned short*)(wsf + A + SBf + A / 2);  // 16 KB
    unsigned short* lo_in = (unsigned short*)(wsf + A + SBf + A);
    unsigned short* hi_in = lo_in + A;                  // bf16
    unsigned short* P0 = hi_in + A;                     // bf16
    unsigned short* P1 = P0 + A;
    unsigned short* P2 = P1 + A;

    float* wllT = out;  // staged in d_out head (overwritten by k_inv_rows)

    k_fwd_rows<<<BT * HS, 256, 0, stream>>>(x, lo_in, hi_in, w_ll, wllT, w1, w2, wB);
    k_cols_mix<<<dim3(BT * WH, 2, 2), 256, 0, stream>>>(lo_in, hi_in, wllT, wB,
                                                        b1, b2, xl, P0, P1, P2);
    k_inv_cols<<<dim3(BT * 7, 4, 2), 256, 0, stream>>>(xl, P0, P1, P2, lo2, hi2);
    k_inv_rows<<<BT * HS, 256, 0, stream>>>(lo2, hi2, out);
}

// Round 13
// 148.075 us; speedup vs baseline: 1.1425x; 1.0124x over previous
//
#include <hip/hip_runtime.h>

#define BT 32
#define CH 64
#define HS 56
#define WS 56
#define HH 28
#define WH 28

// ---------------- filter constants (exact reference values) ----------------
namespace {
constexpr float ISQ2 = 0.70710678118654752440f;
constexpr float F_H0[13] = {-0.0017578125f, 0.0f, 0.022265625f, -0.046875f,
    -0.0482421875f, 0.296875f, 0.55546875f, 0.296875f, -0.0482421875f,
    -0.046875f, 0.022265625f, 0.0f, -0.0017578125f};
constexpr float F_H1[19] = {-7.0626e-05f, 0.0f, 0.00134189f, -0.00188341f,
    -0.0071566f, 0.023856f, 0.0556431f, -0.0516881f, -0.299758f, 0.559431f,
    -0.299758f, -0.0516881f, 0.0556431f, 0.023856f, -0.0071566f,
    -0.00188341f, 0.00134189f, 0.0f, -7.0626e-05f};
constexpr float F_G0[19] = {7.0626e-05f, 0.0f, -0.00134189f, -0.00188341f,
    0.0071566f, 0.023856f, -0.0556431f, -0.0516881f, 0.299758f, 0.559431f,
    0.299758f, -0.0516881f, -0.0556431f, 0.023856f, 0.0071566f,
    -0.00188341f, -0.00134189f, 0.0f, 7.0626e-05f};
constexpr float F_G1[13] = {-0.0017578125f, 0.0f, 0.022265625f, 0.046875f,
    -0.0482421875f, -0.296875f, 0.55546875f, -0.296875f, -0.0482421875f,
    0.046875f, 0.022265625f, 0.0f, -0.0017578125f};
}

__device__ __forceinline__ int symi(int k) {
    k = (k < 0) ? (-1 - k) : k;
    k = (k >= HS) ? (2 * HS - 1 - k) : k;
    return k;
}
__device__ __forceinline__ int symi_lo(int k) { return (k < 0) ? (-1 - k) : k; }
__device__ __forceinline__ int symi_hi(int k) { return (k >= HS) ? (2 * HS - 1 - k) : k; }

__device__ __forceinline__ unsigned short f2bf(float f) {  // RNE bf16
    unsigned u = __float_as_uint(f);
    u += 0x7fffu + ((u >> 16) & 1u);
    return (unsigned short)(u >> 16);
}
__device__ __forceinline__ float bf2f(unsigned short h) {
    return __uint_as_float(((unsigned)h) << 16);
}
// HW packed f32->bf16 RNE (bit-identical to f2bf for finite values)
__device__ __forceinline__ unsigned cvtpk(float lo, float hi) {
    unsigned r;
    asm("v_cvt_pk_bf16_f32 %0, %1, %2" : "=v"(r) : "v"(lo), "v"(hi));
    return r;
}
// unpack 2 packed bf16 (channels c0, c0+1) from one dword
__device__ __forceinline__ float2 bfp2(unsigned u) {
    float2 r;
    r.x = __uint_as_float((u & 0xffffu) << 16);
    r.y = __uint_as_float(u & 0xffff0000u);
    return r;
}
__device__ __forceinline__ unsigned packbf(float a, float b) {
    return (unsigned)f2bf(a) | ((unsigned)f2bf(b) << 16);
}

typedef __attribute__((ext_vector_type(8))) short short8;  // 8 bf16 (4 VGPR)
typedef __attribute__((ext_vector_type(4))) float f32x4;

#define PPOS 784

// ---- K1: forward row filters: x -> lo, hi (bf16).
// Block 0..48: also transpose w_ll -> wllT. Block 49: also precompute bf16
// MFMA weight fragments wB[4][256][8] (B1r,B1i,B2r,B2i per (nb,lane)).
__global__ __launch_bounds__(256) void k_fwd_rows(const float* __restrict__ x,
                                                  unsigned short* __restrict__ lo,
                                                  unsigned short* __restrict__ hi,
                                                  const float* __restrict__ wll,
                                                  float* __restrict__ wllT,
                                                  const float* __restrict__ w1,
                                                  const float* __restrict__ w2,
                                                  unsigned short* __restrict__ wB) {
    int b = blockIdx.x / HS, h = blockIdx.x % HS;
    int strip = threadIdx.x >> 5;        // 0..7 strips of 7 w
    int c0 = (threadIdx.x & 31) * 2;
    int base = (b * HS + h) * WS * CH + c0;
    const float* row = x + base;
    unsigned short* lop = lo + base;
    unsigned short* hip = hi + base;
    int w0s = strip * 7;
    float Wa[19], Wb[19];
#pragma unroll
    for (int t = 0; t < 19; ++t) {
        float2 v = *(const float2*)(row + symi(w0s - 9 + t) * CH);
        Wa[t] = v.x; Wb[t] = v.y;
    }
    float2 nW[7];
#pragma unroll
    for (int u = 0; u < 7; ++u) nW[u] = *(const float2*)(row + symi(w0s + u + 10) * CH);
#pragma unroll
    for (int u = 0; u < 7; ++u) {
        int w = w0s + u;
        float aLo = 0.f, aHi = 0.f, bLo = 0.f, bHi = 0.f;
#pragma unroll
        for (int t = 0; t < 13; ++t) { aLo += F_H0[t] * Wa[3 + t]; bLo += F_H0[t] * Wb[3 + t]; }
#pragma unroll
        for (int t = 0; t < 19; ++t) { aHi += F_H1[t] * Wa[t]; bHi += F_H1[t] * Wb[t]; }
        *(unsigned*)(lop + w * CH) = cvtpk(aLo, bLo);
        *(unsigned*)(hip + w * CH) = cvtpk(aHi, bHi);
#pragma unroll
        for (int t = 0; t < 18; ++t) { Wa[t] = Wa[t + 1]; Wb[t] = Wb[t + 1]; }
        Wa[18] = nW[u].x; Wb[18] = nW[u].y;
    }
    // ---- folded w_ll transpose (uniform per-block branch; 49 blocks) ----
    if (blockIdx.x < 49) {
        __shared__ float tile[64][65];
        int pos0 = blockIdx.x * 64;
        int lp = threadIdx.x & 63, g = threadIdx.x >> 6;
#pragma unroll
        for (int r = 0; r < 16; ++r) {
            int cc = r * 4 + g;
            tile[cc][lp] = wll[cc * (HS * WS) + pos0 + lp];
        }
        __syncthreads();
#pragma unroll
        for (int r = 0; r < 16; ++r) {
            int pl = r * 4 + g;
            wllT[(pos0 + pl) * CH + lp] = tile[lp][pl];
        }
    } else if (blockIdx.x == 49) {
        // ---- weight fragment precompute (bit-identical to old in-kernel) ---
        int tid = threadIdx.x;
        int lane = tid & 63;
        int nb = tid >> 6;
        int quad = lane >> 4, n = lane & 15;
        short8 B1r, B1i, B2r, B2i;
#pragma unroll
        for (int j = 0; j < 8; ++j) {
            int kk = quad * 8 + j;
            int riw = kk >> 4, dd = kk & 15;
            float v1r = w1[nb * 256 + dd * 16 + n];
            float v1i = w1[1024 + nb * 256 + dd * 16 + n];
            float v2r = w2[nb * 256 + dd * 16 + n];
            float v2i = w2[1024 + nb * 256 + dd * 16 + n];
            B1r[j] = (short)f2bf(riw ? -v1i : v1r);
            B1i[j] = (short)f2bf(riw ? v1r : v1i);
            B2r[j] = (short)f2bf(riw ? -v2i : v2r);
            B2i[j] = (short)f2bf(riw ? v2r : v2i);
        }
        *(short8*)(wB + (0 * 256 + tid) * 8) = B1r;
        *(short8*)(wB + (1 * 256 + tid) * 8) = B1i;
        *(short8*)(wB + (2 * 256 + tid) * 8) = B2r;
        *(short8*)(wB + (3 * 256 + tid) * 8) = B2i;
    }
}

// ---- K2: FUSED column filters + q2c + MFMA mix, templated on (ZM, HF).
// ZM=0: lo->P0 (planes s0,s5); ZM=1: hi->P1,P2 (s2,s3 / s1,s4).
template <int ZM, int HF>
__device__ __forceinline__ void cols_mix_body(
    unsigned short (&qTb)[2][4][14][64], unsigned short (&pA)[8][14][72],
    const unsigned short* __restrict__ lo_in,
    const unsigned short* __restrict__ hi_in, const float* __restrict__ wllT,
    const unsigned short* __restrict__ wB, const float* __restrict__ b1,
    const float* __restrict__ b2, unsigned short* __restrict__ xl,
    unsigned short* __restrict__ P0, unsigned short* __restrict__ P1,
    unsigned short* __restrict__ P2) {
    unsigned short (*l1a)[16][36] =
        reinterpret_cast<unsigned short(*)[16][36]>(&qTb[0][0][0][0]);
    unsigned short (*l1b)[16][36] = l1a + 4;

    int b = blockIdx.x / WH, wp = blockIdx.x % WH;
    int w0 = 2 * wp, tid = threadIdx.x;
    int q = tid >> 6, c = tid & 63;
    int rp = q >> 1, jc = q & 1;
    const unsigned short* srcp = ZM ? hi_in : lo_in;
    const unsigned short* colbase = srcp + (b * HS) * WS * CH + (w0 + jc) * CH + c;
    {
        int hstart = HF * 28 + rp;
        float W[19];
#pragma unroll
        for (int t = 0; t < 19; ++t) {
            int r = (HF == 0) ? symi_lo(hstart - 9 + t) : (hstart - 9 + t);
            W[t] = bf2f(colbase[r * (WS * CH)]);
        }
#pragma unroll
        for (int rnd = 0; rnd < 2; ++rnd) {
            float nW0[7], nW1[7], nwll[7];
            int ii0 = rnd * 7;
#pragma unroll
            for (int u = 0; u < 7; ++u) {
                int h = hstart + 2 * (ii0 + u);
                int r0 = (HF == 0) ? (h + 10) : symi_hi(h + 10);
                int r1 = (HF == 0) ? (h + 11) : symi_hi(h + 11);
                nW0[u] = bf2f(colbase[r0 * (WS * CH)]);
                nW1[u] = bf2f(colbase[r1 * (WS * CH)]);
            }
            if (ZM == 0) {
#pragma unroll
                for (int u = 0; u < 7; ++u)
                    nwll[u] = wllT[((hstart + 2 * (ii0 + u)) * WS + (w0 + jc)) * CH + c];
            }
#pragma unroll
            for (int u = 0; u < 7; ++u) {
                const int ii = ii0 + u;
                int h = hstart + 2 * ii;
                float v0 = 0.f, v1 = 0.f;
#pragma unroll
                for (int t = 0; t < 13; ++t) v0 += F_H0[t] * W[(2 * ii + 3 + t) % 19];
#pragma unroll
                for (int t = 0; t < 19; ++t) v1 += F_H1[t] * W[(2 * ii + t) % 19];
                if (ZM == 0) {
                    unsigned pk = cvtpk(v0 * nwll[u], v1);
                    xl[((b * HS + h) * WS + (w0 + jc)) * CH + c] = (unsigned short)pk;
                    qTb[0][q][ii][c] = (unsigned short)(pk >> 16);
                } else {
                    unsigned pk = cvtpk(v0, v1);
                    qTb[0][q][ii][c] = (unsigned short)pk;          // hl
                    qTb[1][q][ii][c] = (unsigned short)(pk >> 16);  // hh
                }
                W[(2 * ii) % 19] = nW0[u];
                W[(2 * ii + 1) % 19] = nW1[u];
            }
        }
    }
    __syncthreads();
    // fused q2c + bf16 pack into pA. Local plane maps:
    //   ZM=0: role -> local role (global 0,1,10,11)
    //   ZM=1: src0(hl) -> local 2+role (global 4..7);
    //         src1(hh) -> local role<2?role:4+role (global 2,3,8,9)
    {
        int qq = tid >> 5;                 // 0..7
        int role = qq & 3, half = qq >> 2; // ii 0..6 / 7..13
        int c0 = (tid & 31) * 2;
        int rowA = role & 1, rowB = 3 - (role & 1);
        float sgn = (role == 1 || role == 2) ? 1.f : -1.f;
        if (ZM == 0) {
#pragma unroll
            for (int g = 0; g < 7; ++g) {
                int ii = half * 7 + g;
                float2 av = bfp2(*(const unsigned*)&qTb[0][rowA][ii][c0]);
                float2 bv = bfp2(*(const unsigned*)&qTb[0][rowB][ii][c0]);
                *(unsigned*)&pA[role][ii][c0] =
                    cvtpk((av.x + sgn * bv.x) * ISQ2, (av.y + sgn * bv.y) * ISQ2);
            }
        } else {
#pragma unroll
            for (int src = 0; src < 2; ++src) {
                int pl = (src == 0) ? (2 + role) : ((role < 2) ? role : (4 + role));
#pragma unroll
                for (int g = 0; g < 7; ++g) {
                    int ii = half * 7 + g;
                    float2 av = bfp2(*(const unsigned*)&qTb[src][rowA][ii][c0]);
                    float2 bv = bfp2(*(const unsigned*)&qTb[src][rowB][ii][c0]);
                    *(unsigned*)&pA[pl][ii][c0] =
                        cvtpk((av.x + sgn * bv.x) * ISQ2, (av.y + sgn * bv.y) * ISQ2);
                }
            }
        }
    }
    __syncthreads();   // pA complete; qTb dead (l1a/l1b alias it)

    // ---- mix phase: weight fragments from precomputed wB (4x dwordx4)
    int lane = tid & 63;
    int wv = tid >> 6;
    int nb = __builtin_amdgcn_readfirstlane(wv);
    int quad = lane >> 4;
    int n = lane & 15;
    int rix = quad >> 1, dlo = (quad & 1) * 8;
    int chb = nb * 16 + dlo;
    int npos = (n < 14) ? n : 0;   // clamp: rows 14,15 discarded at store

    short8 B1r = *(const short8*)(wB + (0 * 256 + tid) * 8);
    short8 B1i = *(const short8*)(wB + (1 * 256 + tid) * 8);
    short8 B2r = *(const short8*)(wB + (2 * 256 + tid) * 8);
    short8 B2i = *(const short8*)(wB + (3 * 256 + tid) * 8);
    float bias1r = b1[nb * 16 + n], bias1i = b1[64 + nb * 16 + n];
    float bias2r = b2[nb * 16 + n], bias2i = b2[64 + nb * 16 + n];

    auto mixprod = [&](int aP, int bP, unsigned short* __restrict__ Pd) {
        short8 A1a = *(const short8*)&pA[aP][npos][chb];
        short8 A1b = *(const short8*)&pA[bP][npos][chb];
        f32x4 a1r = {bias1r, bias1r, bias1r, bias1r};
        f32x4 a1i = {bias1i, bias1i, bias1i, bias1i};
        f32x4 b1r_ = a1r, b1i_ = a1i;
        a1r = __builtin_amdgcn_mfma_f32_16x16x32_bf16(A1a, B1r, a1r, 0, 0, 0);
        a1i = __builtin_amdgcn_mfma_f32_16x16x32_bf16(A1a, B1i, a1i, 0, 0, 0);
        b1r_ = __builtin_amdgcn_mfma_f32_16x16x32_bf16(A1b, B1r, b1r_, 0, 0, 0);
        b1i_ = __builtin_amdgcn_mfma_f32_16x16x32_bf16(A1b, B1i, b1i_, 0, 0, 0);
#pragma unroll
        for (int r = 0; r < 4; ++r) {
            int pos = quad * 4 + r;
            unsigned pka = cvtpk(fmaxf(a1r[r], 0.f), fmaxf(a1i[r], 0.f));
            unsigned pkb = cvtpk(fmaxf(b1r_[r], 0.f), fmaxf(b1i_[r], 0.f));
            l1a[wv][pos][n] = (unsigned short)pka;
            l1a[wv][pos][16 + n] = (unsigned short)(pka >> 16);
            l1b[wv][pos][n] = (unsigned short)pkb;
            l1b[wv][pos][16 + n] = (unsigned short)(pkb >> 16);
        }
        union { short8 s8; uint2 u2[2]; } a2a, a2b;
        const unsigned short* rowpa = &l1a[wv][n][0];
        const unsigned short* rowpb = &l1b[wv][n][0];
        a2a.u2[0] = *(const uint2*)(rowpa + quad * 8);
        a2a.u2[1] = *(const uint2*)(rowpa + quad * 8 + 4);
        a2b.u2[0] = *(const uint2*)(rowpb + quad * 8);
        a2b.u2[1] = *(const uint2*)(rowpb + quad * 8 + 4);
        f32x4 aAr = {bias2r, bias2r, bias2r, bias2r};
        f32x4 aAi = {bias2i, bias2i, bias2i, bias2i};
        f32x4 aBr = aAr, aBi = aAi;
        aAr = __builtin_amdgcn_mfma_f32_16x16x32_bf16(a2a.s8, B2r, aAr, 0, 0, 0);
        aAi = __builtin_amdgcn_mfma_f32_16x16x32_bf16(a2a.s8, B2i, aAi, 0, 0, 0);
        aBr = __builtin_amdgcn_mfma_f32_16x16x32_bf16(a2b.s8, B2r, aBr, 0, 0, 0);
        aBi = __builtin_amdgcn_mfma_f32_16x16x32_bf16(a2b.s8, B2i, aBi, 0, 0, 0);
#pragma unroll
        for (int r = 0; r < 4; ++r) {
            int m = quad * 4 + r;
            if (m < 14) {
                int iig = HF * 14 + m;
                int o = ((b * HS + 2 * iig) * WS + 2 * wp) * CH + nb * 16 + n;
                unsigned pk0 = cvtpk((aAr[r] + aBr[r]) * ISQ2, (aAi[r] + aBi[r]) * ISQ2);
                unsigned pk1 = cvtpk((aAi[r] - aBi[r]) * ISQ2, (aBr[r] - aAr[r]) * ISQ2);
                Pd[o] = (unsigned short)pk0;
                Pd[o + CH] = (unsigned short)(pk0 >> 16);
                Pd[o + WS * CH] = (unsigned short)pk1;
                Pd[o + WS * CH + CH] = (unsigned short)(pk1 >> 16);
            }
        }
    };

    if (ZM == 0) {
        mixprod(rix, 2 + rix, P0);            // s0 x s5
    } else {
        mixprod(2 + rix, 4 + rix, P1);        // s2 x s3
        mixprod(rix, 6 + rix, P2);            // s1 x s4
    }
}

__global__ __launch_bounds__(256) void k_cols_mix(
    const unsigned short* __restrict__ lo_in,
    const unsigned short* __restrict__ hi_in, const float* __restrict__ wllT,
    const unsigned short* __restrict__ wB, const float* __restrict__ b1,
    const float* __restrict__ b2, unsigned short* __restrict__ xl,
    unsigned short* __restrict__ P0, unsigned short* __restrict__ P1,
    unsigned short* __restrict__ P2) {
    __shared__ __align__(16) unsigned short qTb[2][4][14][64];  // 14.3 KB
    __shared__ __align__(16) unsigned short pA[8][14][72];      // 16.1 KB
    if (blockIdx.z == 0) {
        if (blockIdx.y == 0)
            cols_mix_body<0, 0>(qTb, pA, lo_in, hi_in, wllT, wB, b1, b2, xl, P0, P1, P2);
        else
            cols_mix_body<0, 1>(qTb, pA, lo_in, hi_in, wllT, wB, b1, b2, xl, P0, P1, P2);
    } else {
        if (blockIdx.y == 0)
            cols_mix_body<1, 0>(qTb, pA, lo_in, hi_in, wllT, wB, b1, b2, xl, P0, P1, P2);
        else
            cols_mix_body<1, 1>(qTb, pA, lo_in, hi_in, wllT, wB, b1, b2, xl, P0, P1, P2);
    }
}

// ---- K4: inverse column pass, templated on (MODE, HF):
//   MODE=0: lo2 = G0col(xl bf16) + G1col(P0);  MODE=1: hi2 = G0col(P1) + G1col(P2)
// HF in {0..3}: h0 = HF*14 compile-time -> all row indices constant; reflection
// one-sided (HF=0 low only, HF=3 high only, HF=1,2 none) -> symi eliminated
// and load addresses fold to base+imm. 2-deep pipelined groups {4,4,4,2}.
template <int MODE, int HF>
__device__ __forceinline__ void inv_cols_body(
    const unsigned short* __restrict__ xl, const unsigned short* __restrict__ P0,
    const unsigned short* __restrict__ P1, const unsigned short* __restrict__ P2,
    unsigned short* __restrict__ lo2, unsigned short* __restrict__ hi2) {
    int b = blockIdx.x / 7, wg = blockIdx.x % 7;
    int wl = threadIdx.x >> 5, l = threadIdx.x & 31;
    int c0 = l * 2;
    int w = wg * 8 + wl;
    int base = (b * HS) * WS * CH + w * CH + c0;
    const int st = WS * CH;
    const unsigned short* Ap = (MODE == 0) ? xl : P1;
    const unsigned short* Bp = (MODE == 0) ? P0 : P2;
    unsigned short* outp = (MODE == 0) ? lo2 : hi2;
    auto ref = [](int k) -> int {
        if (HF == 0) return (k < 0) ? (-1 - k) : k;
        if (HF == 3) return (k >= HS) ? (2 * HS - 1 - k) : k;
        return k;
    };
    auto ldA = [&](int r) -> float2 {
        return bfp2(*(const unsigned*)(Ap + base + r * st));
    };
    auto ldB = [&](int r) -> float2 {
        return bfp2(*(const unsigned*)(Bp + base + r * st));
    };
    const int h0 = HF * 14;
    float Aa[19], Ab[19], Ba[13], Bb[13];
#pragma unroll
    for (int t = 0; t < 19; ++t) { float2 v = ldA(ref(h0 - 9 + t)); Aa[t] = v.x; Ab[t] = v.y; }
#pragma unroll
    for (int t = 0; t < 13; ++t) { float2 v = ldB(ref(h0 - 6 + t)); Ba[t] = v.x; Bb[t] = v.y; }
    float2 pa0[4], pb0[4], pa1[4], pb1[4];
#define LDG(bA, bB, OFF, CNT)                                                   \
    {                                                                           \
        _Pragma("unroll") for (int u = 0; u < (CNT); ++u)                       \
            bA[u] = ldA(ref(h0 + (OFF) + u + 10));                              \
        _Pragma("unroll") for (int u = 0; u < (CNT); ++u)                       \
            bB[u] = ldB(ref(h0 + (OFF) + u + 7));                               \
    }
#define CPG(bA, bB, OFF, CNT)                                                   \
    {                                                                           \
        _Pragma("unroll") for (int u = 0; u < (CNT); ++u) {                     \
            int h = h0 + (OFF) + u;                                             \
            float acca = 0.f, accb = 0.f;                                       \
            _Pragma("unroll") for (int t = 0; t < 19; ++t) {                    \
                acca += F_G0[t] * Aa[t]; accb += F_G0[t] * Ab[t];               \
            }                                                                   \
            _Pragma("unroll") for (int t = 0; t < 13; ++t) {                    \
                acca += F_G1[t] * Ba[t]; accb += F_G1[t] * Bb[t];               \
            }                                                                   \
            *(unsigned*)(outp + base + h * st) = cvtpk(acca, accb);             \
            _Pragma("unroll") for (int t = 0; t < 18; ++t) {                    \
                Aa[t] = Aa[t + 1]; Ab[t] = Ab[t + 1];                           \
            }                                                                   \
            _Pragma("unroll") for (int t = 0; t < 12; ++t) {                    \
                Ba[t] = Ba[t + 1]; Bb[t] = Bb[t + 1];                           \
            }                                                                   \
            Aa[18] = bA[u].x; Ab[18] = bA[u].y;                                 \
            Ba[12] = bB[u].x; Bb[12] = bB[u].y;                                 \
        }                                                                       \
    }
    LDG(pa0, pb0, 0, 4) LDG(pa1, pb1, 4, 4)
    CPG(pa0, pb0, 0, 4) LDG(pa0, pb0, 8, 4)
    CPG(pa1, pb1, 4, 4) LDG(pa1, pb1, 12, 2)
    CPG(pa0, pb0, 8, 4)
    CPG(pa1, pb1, 12, 2)
#undef LDG
#undef CPG
}

template <int MODE>
__device__ __forceinline__ void inv_cols_hf(
    const unsigned short* __restrict__ xl, const unsigned short* __restrict__ P0,
    const unsigned short* __restrict__ P1, const unsigned short* __restrict__ P2,
    unsigned short* __restrict__ lo2, unsigned short* __restrict__ hi2) {
    switch (blockIdx.y) {
        case 0: inv_cols_body<MODE, 0>(xl, P0, P1, P2, lo2, hi2); break;
        case 1: inv_cols_body<MODE, 1>(xl, P0, P1, P2, lo2, hi2); break;
        case 2: inv_cols_body<MODE, 2>(xl, P0, P1, P2, lo2, hi2); break;
        default: inv_cols_body<MODE, 3>(xl, P0, P1, P2, lo2, hi2); break;
    }
}

__global__ __launch_bounds__(256) void k_inv_cols(
    const unsigned short* __restrict__ xl, const unsigned short* __restrict__ P0,
    const unsigned short* __restrict__ P1, const unsigned short* __restrict__ P2,
    unsigned short* __restrict__ lo2, unsigned short* __restrict__ hi2) {
    if (blockIdx.z == 0)
        inv_cols_hf<0>(xl, P0, P1, P2, lo2, hi2);
    else
        inv_cols_hf<1>(xl, P0, P1, P2, lo2, hi2);
}

// ---- K5: inverse row filters (bf16 in) -> out (fp32), 2ch/thread, batched
__global__ __launch_bounds__(256) void k_inv_rows(
    const unsigned short* __restrict__ lo2,
    const unsigned short* __restrict__ hi2, float* __restrict__ out) {
    int b = blockIdx.x / HS, h = blockIdx.x % HS;
    int strip = threadIdx.x >> 5;        // 0..7 strips of 7 w
    int c0 = (threadIdx.x & 31) * 2;
    int base = (b * HS + h) * WS * CH + c0;
    const unsigned short* rlo = lo2 + base;
    const unsigned short* rhi = hi2 + base;
    float* op = out + base;
    int w0s = strip * 7;
    float Aa[19], Ab[19], Ba[13], Bb[13];
#pragma unroll
    for (int t = 0; t < 19; ++t) {
        float2 v = bfp2(*(const unsigned*)(rlo + symi(w0s - 9 + t) * CH));
        Aa[t] = v.x; Ab[t] = v.y;
    }
#pragma unroll
    for (int t = 0; t < 13; ++t) {
        float2 v = bfp2(*(const unsigned*)(rhi + symi(w0s - 6 + t) * CH));
        Ba[t] = v.x; Bb[t] = v.y;
    }
    float2 nA[7], nB[7];
#pragma unroll
    for (int u = 0; u < 7; ++u) nA[u] = bfp2(*(const unsigned*)(rlo + symi(w0s + u + 10) * CH));
#pragma unroll
    for (int u = 0; u < 7; ++u) nB[u] = bfp2(*(const unsigned*)(rhi + symi(w0s + u + 7) * CH));
#pragma unroll
    for (int u = 0; u < 7; ++u) {
        int w = w0s + u;
        float acca = 0.f, accb = 0.f;
#pragma unroll
        for (int t = 0; t < 19; ++t) { acca += F_G0[t] * Aa[t]; accb += F_G0[t] * Ab[t]; }
#pragma unroll
        for (int t = 0; t < 13; ++t) { acca += F_G1[t] * Ba[t]; accb += F_G1[t] * Bb[t]; }
        float2 ov; ov.x = acca; ov.y = accb;
        *(float2*)(op + w * CH) = ov;
#pragma unroll
        for (int t = 0; t < 18; ++t) { Aa[t] = Aa[t + 1]; Ab[t] = Ab[t + 1]; }
#pragma unroll
        for (int t = 0; t < 12; ++t) { Ba[t] = Ba[t + 1]; Bb[t] = Bb[t + 1]; }
        Aa[18] = nA[u].x; Ab[18] = nA[u].y;
        Ba[12] = nB[u].x; Bb[12] = nB[u].y;
    }
}

extern "C" void kernel_launch(void* const* d_in, const int* in_sizes, int n_in,
                              void* d_out, int out_size, void* d_ws, size_t ws_size,
                              hipStream_t stream) {
    const float* x = (const float*)d_in[0];
    const float* w_ll = (const float*)d_in[1];
    const float* w1 = (const float*)d_in[2];
    const float* w2 = (const float*)d_in[3];
    const float* b1 = (const float*)d_in[4];
    const float* b2 = (const float*)d_in[5];
    float* out = (float*)d_out;

    // workspace map (float units). A = 6,422,528; SBf = 9,633,792.
    // xl(bf16, region A) | lo2 bf16 (SBf region) | hi2 bf16 (A/2) | wB (gap)
    // | lo_in | hi_in | P0 | P1 | P2
    const size_t A = (size_t)BT * HS * WS * CH;
    const size_t SBf = (size_t)12 * 64 * BT * PPOS / 2;
    float* wsf = (float*)d_ws;
    unsigned short* xl = (unsigned short*)wsf;          // bf16 (region oversized)
    unsigned short* lo2 = (unsigned short*)(wsf + A);
    unsigned short* hi2 = (unsigned short*)(wsf + A + SBf);
    unsigned short* wB = (unsigned short*)(wsf + A + SBf + A / 2);  // 16 KB
    unsigned short* lo_in = (unsigned short*)(wsf + A + SBf + A);
    unsigned short* hi_in = lo_in + A;                  // bf16
    unsigned short* P0 = hi_in + A;                     // bf16
    unsigned short* P1 = P0 + A;
    unsigned short* P2 = P1 + A;

    float* wllT = out;  // staged in d_out head (overwritten by k_inv_rows)

    k_fwd_rows<<<BT * HS, 256, 0, stream>>>(x, lo_in, hi_in, w_ll, wllT, w1, w2, wB);
    k_cols_mix<<<dim3(BT * WH, 2, 2), 256, 0, stream>>>(lo_in, hi_in, wllT, wB,
                                                        b1, b2, xl, P0, P1, P2);
    k_inv_cols<<<dim3(BT * 7, 4, 2), 256, 0, stream>>>(xl, P0, P1, P2, lo2, hi2);
    k_inv_rows<<<BT * HS, 256, 0, stream>>>(lo2, hi2, out);
}